// Round 1
// baseline (267.474 us; speedup 1.0000x reference)
//
#include <hip/hip_runtime.h>

#define NNODES 50000
#define NEDGES 800000
#define CHUNK 3125          // edges per CSR block (256 blocks * 3125 = 800000)

typedef __attribute__((ext_vector_type(8))) short short8;
typedef __attribute__((ext_vector_type(4))) float floatx4;
typedef __attribute__((ext_vector_type(8))) _Float16 f16x8;

// async global->LDS, 16B per lane (global_load_lds_dwordx4).
// LDS dest MUST be wave-uniform base + lane*16.
__device__ __forceinline__ void async16(const void* g, void* l) {
    __builtin_amdgcn_global_load_lds(
        (const __attribute__((address_space(1))) unsigned int*)g,
        (__attribute__((address_space(3))) unsigned int*)l, 16, 0, 0);
}

__device__ __forceinline__ void split_bf16(float v, short& hi, short& lo) {
    unsigned u = __float_as_uint(v);
    unsigned hu = u & 0xffff0000u;
    hi = (short)(hu >> 16);
    float r = v - __uint_as_float(hu);
    lo = (short)(__float_as_uint(r) >> 16);
}

// ------ prep: weight transpose/split + coarse histogram ------------------

#define PREP_WBLK 224
#define PREP_TOT  (PREP_WBLK + 256)

__global__ __launch_bounds__(256) void k_prep(
    const float* __restrict__ W0, short* __restrict__ W0h, short* __restrict__ W0l,
    const float* __restrict__ W1, short* __restrict__ W1h, short* __restrict__ W1l,
    const float* __restrict__ W2, short* __restrict__ W2h, short* __restrict__ W2l,
    const int* __restrict__ dst, int* __restrict__ hist2d) {
    int b = blockIdx.x, t = threadIdx.x;
    if (b < PREP_WBLK) {
        int id = b * 256 + t;
        const float* W; short *Wh, *Wl; int K, F;
        if (id < 32768) { W = W0; Wh = W0h; Wl = W0l; K = 256; F = 128; }
        else if (id < 49152) { id -= 32768; W = W1; Wh = W1h; Wl = W1l; K = 128; F = 128; }
        else if (id < 57344) { id -= 49152; W = W2; Wh = W2h; Wl = W2l; K = 128; F = 64; }
        else return;
        int f = id / K, k = id - f * K;
        short h, l;
        split_bf16(W[(size_t)k * F + f], h, l);
        Wh[id] = h;
        Wl[id] = l;
    } else {
        // per-block coarse histogram of dst>>8 (no global atomics)
        __shared__ int h[256];
        int bb = b - PREP_WBLK;
        h[t] = 0;
        __syncthreads();
        int e0 = bb * CHUNK;
#pragma unroll
        for (int k = 0; k < 13; k++) {
            int o = k * 256 + t;
            if (o < CHUNK) atomicAdd(&h[dst[e0 + o] >> 8], 1);
        }
        __syncthreads();
        hist2d[bb * 256 + t] = h[t];
    }
}

// P2 (self-scanning): deterministic coarse scatter. NEW: LDS-staged bucket
// write — edges placed into LDS ordered by coarse bin, then flushed with
// consecutive threads -> ~12-entry contiguous bursts per bin instead of
// isolated scattered dwords (cuts TCC RMW line traffic ~4x).
__global__ __launch_bounds__(256) void k_p2(const int* __restrict__ src,
                                            const int* __restrict__ dst,
                                            const int* __restrict__ hist2d,
                                            unsigned* __restrict__ buck) {
    __shared__ int ex[256], lex[256], lcur[256], delta[256];
    __shared__ unsigned lbuck[CHUNK];
    __shared__ int gd[CHUNK];
    int t = threadIdx.x, b = blockIdx.x;
    int tot = 0, pre = 0, mine = 0;
    for (int bb = 0; bb < 256; bb++) {
        int v = hist2d[bb * 256 + t];
        tot += v;
        pre += (bb < b) ? v : 0;
        if (bb == b) mine = v;
    }
    ex[t] = tot;
    lex[t] = mine;
    __syncthreads();
    // dual inclusive scan over t: ex (column totals), lex (this block's row)
    for (int o = 1; o < 256; o <<= 1) {
        int x1 = (t >= o) ? ex[t - o] : 0;
        int x2 = (t >= o) ? lex[t - o] : 0;
        __syncthreads();
        ex[t] += x1;
        lex[t] += x2;
        __syncthreads();
    }
    int cur0 = (ex[t] - tot) + pre;      // global base of bin t for this block
    int lexcl = lex[t] - mine;           // local base of bin t inside this block
    lcur[t] = lexcl;
    delta[t] = cur0 - lexcl;             // gaddr = delta[bin] + local_pos
    __syncthreads();
    int e0 = b * CHUNK;
#pragma unroll
    for (int k = 0; k < 13; k++) {
        int o = k * 256 + t;
        if (o < CHUNK) {
            int s = src[e0 + o], d = dst[e0 + o];
            int bin = d >> 8;
            int lp = atomicAdd(&lcur[bin], 1);   // LDS atomic only
            lbuck[lp] = (unsigned)s | ((unsigned)(d & 255) << 16);
            gd[lp] = delta[bin] + lp;
        }
    }
    __syncthreads();
    // flush: consecutive o -> mostly-consecutive global addresses
#pragma unroll
    for (int k = 0; k < 13; k++) {
        int o = k * 256 + t;
        if (o < CHUNK) buck[gd[o]] = lbuck[o];
    }
}

// P3 (self-scanning): finalize coarse bin b -> rowptr/dinv/ssrc.
__global__ __launch_bounds__(256) void k_p3(const unsigned* __restrict__ buck,
                                            const int* __restrict__ hist2d,
                                            int* __restrict__ rowptr,
                                            float* __restrict__ dinv,
                                            int* __restrict__ ssrc) {
    __shared__ int ex[256], cur[256], h[256], sS0[1], sS[1];
    int t = threadIdx.x, b = blockIdx.x;
    int tot = 0;
    for (int bb = 0; bb < 256; bb++) tot += hist2d[bb * 256 + t];
    ex[t] = tot;
    __syncthreads();
    for (int o = 1; o < 256; o <<= 1) {
        int xx = (t >= o) ? ex[t - o] : 0;
        __syncthreads();
        ex[t] += xx;
        __syncthreads();
    }
    if (t == b) { sS0[0] = ex[t] - tot; sS[0] = tot; }
    h[t] = 0;
    __syncthreads();
    int s0 = sS0[0], S = sS[0];
    for (int i = t; i < S; i += 256)
        atomicAdd(&h[(buck[s0 + i] >> 16) & 255], 1);
    __syncthreads();
    int v = h[t];
    ex[t] = v;
    __syncthreads();
    for (int o = 1; o < 256; o <<= 1) {
        int xx = (t >= o) ? ex[t - o] : 0;
        __syncthreads();
        ex[t] += xx;
        __syncthreads();
    }
    int excl = ex[t] - v;
    int n = b * 256 + t;
    if (n < NNODES) {
        rowptr[n] = s0 + excl;
        dinv[n] = rsqrtf((float)v + 1.0f);
    }
    if (b == 0 && t == 0) rowptr[NNODES] = NEDGES;
    cur[t] = excl;
    __syncthreads();
    for (int i = t; i < S; i += 256) {
        unsigned pk = buck[s0 + i];
        int dl = (pk >> 16) & 255;
        int p = atomicAdd(&cur[dl], 1);
        ssrc[s0 + p] = (int)(pk & 0xFFFFu);
    }
}

// ------ gemm0: g16 = fp16((x @ W0) * dinv[row]) --------------------------
// Direct fp32 x read + in-register split, XOR-swizzled LDS-A (proven R9).

__global__ __launch_bounds__(256) void k_gemm0(
    const float* __restrict__ x, const short* __restrict__ Bh,
    const short* __restrict__ Bl, const float* __restrict__ dinv,
    _Float16* __restrict__ g16) {
    __shared__ __align__(16) short sAh[64 * 64], sAl[64 * 64];
    __shared__ __align__(16) short sBh[128 * 64], sBl[128 * 64];
    const int t = threadIdx.x, lane = t & 63, w = t >> 6;
    const int row0 = blockIdx.x * 64;
    const int lr = lane >> 3, lz = lane & 7;
    const int swz = (lz ^ lr) * 8;
    const int fr = lane & 15, fq = lane >> 4;
    floatx4 acc[8] = {};
    const int ar = t >> 2, ac = t & 3;
    int garow = row0 + ar;
    if (garow >= NNODES) garow = NNODES - 1;
    const float* xrow = x + (size_t)garow * 256 + ac * 16;

    for (int k0 = 0; k0 < 256; k0 += 64) {
        const float4* xp = (const float4*)(xrow + k0);
        float4 f0 = xp[0], f1 = xp[1], f2 = xp[2], f3 = xp[3];
        float va[16] = {f0.x, f0.y, f0.z, f0.w, f1.x, f1.y, f1.z, f1.w,
                        f2.x, f2.y, f2.z, f2.w, f3.x, f3.y, f3.z, f3.w};
        short8 h0, h1, l0, l1;
#pragma unroll
        for (int j = 0; j < 8; j++) {
            short h, l;
            split_bf16(va[j], h, l);     h0[j] = h; l0[j] = l;
            split_bf16(va[8 + j], h, l); h1[j] = h; l1[j] = l;
        }
        int c0 = ac * 2;
        *(short8*)&sAh[ar * 64 + ((c0 ^ (ar & 7)) * 8)] = h0;
        *(short8*)&sAh[ar * 64 + (((c0 + 1) ^ (ar & 7)) * 8)] = h1;
        *(short8*)&sAl[ar * 64 + ((c0 ^ (ar & 7)) * 8)] = l0;
        *(short8*)&sAl[ar * 64 + (((c0 + 1) ^ (ar & 7)) * 8)] = l1;
#pragma unroll
        for (int jj = 0; jj < 4; jj++) {
            int j = w * 4 + jj;
            size_t go = (size_t)(j * 8 + lr) * 256 + k0 + swz;
            async16(&Bh[go], &sBh[j * 512 + lane * 8]);
            async16(&Bl[go], &sBl[j * 512 + lane * 8]);
        }
        __syncthreads();
#pragma unroll
        for (int ks = 0; ks < 2; ks++) {
            int R = w * 16 + fr;
            int ca = ((ks * 4 + fq) ^ (R & 7)) * 8;
            short8 ah = *(const short8*)&sAh[R * 64 + ca];
            short8 al = *(const short8*)&sAl[R * 64 + ca];
#pragma unroll
            for (int nt = 0; nt < 8; nt++) {
                int n = nt * 16 + fr;
                int cb = ((ks * 4 + fq) ^ (n & 7)) * 8;
                short8 bh = *(const short8*)&sBh[n * 64 + cb];
                short8 bl = *(const short8*)&sBl[n * 64 + cb];
                acc[nt] = __builtin_amdgcn_mfma_f32_16x16x32_bf16(ah, bh, acc[nt], 0, 0, 0);
                acc[nt] = __builtin_amdgcn_mfma_f32_16x16x32_bf16(ah, bl, acc[nt], 0, 0, 0);
                acc[nt] = __builtin_amdgcn_mfma_f32_16x16x32_bf16(al, bh, acc[nt], 0, 0, 0);
            }
        }
        __syncthreads();
    }
#pragma unroll
    for (int rr = 0; rr < 4; rr++) {
        int gw = row0 + w * 16 + fq * 4 + rr;
        if (gw < NNODES) {
            float dv = dinv[gw];
#pragma unroll
            for (int nt = 0; nt < 8; nt++)
                g16[(size_t)gw * 128 + nt * 16 + fr] =
                    (_Float16)(acc[nt][rr] * dv);
        }
    }
}

// ------ gemm (layers 1/2): g16 = fp16((A @ W) * dinv), proven R8 ---------

template <int BN>
__global__ __launch_bounds__(256) void k_gemm2(
    const short* __restrict__ Ah, const short* __restrict__ Al,
    const short* __restrict__ Bh, const short* __restrict__ Bl,
    const float* __restrict__ dinv, _Float16* __restrict__ g16, int K) {
    constexpr int BM = 64, BK = 64;
    constexpr int NT = BN / 16;
    __shared__ __align__(16) short sAh[BM * BK], sAl[BM * BK];
    __shared__ __align__(16) short sBh[BN * BK], sBl[BN * BK];

    const int tid = threadIdx.x, lane = tid & 63, w = tid >> 6;
    const int row0 = blockIdx.x * BM;
    const int lr = lane >> 3;
    const int lz = lane & 7;
    const int swz = (lz ^ lr) * 8;
    const int fr = lane & 15, fq = lane >> 4;

    floatx4 acc[NT] = {};

    for (int k0 = 0; k0 < K; k0 += BK) {
#pragma unroll
        for (int jj = 0; jj < 2; jj++) {
            int j = w * 2 + jj;
            int grow = row0 + j * 8 + lr;
            if (grow >= NNODES) grow = NNODES - 1;
            size_t go = (size_t)grow * K + k0 + swz;
            async16(&Ah[go], &sAh[j * 8 * BK + lane * 8]);
            async16(&Al[go], &sAl[j * 8 * BK + lane * 8]);
        }
#pragma unroll
        for (int jj = 0; jj < BN / 32; jj++) {
            int j = w * (BN / 32) + jj;
            size_t go = (size_t)(j * 8 + lr) * K + k0 + swz;
            async16(&Bh[go], &sBh[j * 8 * BK + lane * 8]);
            async16(&Bl[go], &sBl[j * 8 * BK + lane * 8]);
        }
        __syncthreads();

#pragma unroll
        for (int ks = 0; ks < 2; ks++) {
            int R = w * 16 + fr;
            int ca = ((ks * 4 + fq) ^ (R & 7)) * 8;
            short8 ah = *(const short8*)&sAh[R * BK + ca];
            short8 al = *(const short8*)&sAl[R * BK + ca];
#pragma unroll
            for (int nt = 0; nt < NT; nt++) {
                int n = nt * 16 + fr;
                int cb = ((ks * 4 + fq) ^ (n & 7)) * 8;
                short8 bh = *(const short8*)&sBh[n * BK + cb];
                short8 bl = *(const short8*)&sBl[n * BK + cb];
                acc[nt] = __builtin_amdgcn_mfma_f32_16x16x32_bf16(ah, bh, acc[nt], 0, 0, 0);
                acc[nt] = __builtin_amdgcn_mfma_f32_16x16x32_bf16(ah, bl, acc[nt], 0, 0, 0);
                acc[nt] = __builtin_amdgcn_mfma_f32_16x16x32_bf16(al, bh, acc[nt], 0, 0, 0);
            }
        }
        __syncthreads();
    }

#pragma unroll
    for (int rr = 0; rr < 4; rr++) {
        int grow = row0 + w * 16 + fq * 4 + rr;
        if (grow < NNODES) {
            float dv = dinv[grow];
#pragma unroll
            for (int nt = 0; nt < NT; nt++)
                g16[(size_t)grow * BN + nt * 16 + fr] =
                    (_Float16)(acc[nt][rr] * dv);
        }
    }
}

// ------ Aggregation: wave-per-node, register edge list (NEW) -------------
// One node per wave (4 nodes/block). The node's edge list is held one entry
// per lane in a register; each wave step broadcasts ES=64/F8 sources via
// __shfl (bpermute) and gathers ES full rows with all 64 lanes active.
// Wave-uniform trip count -> no divergence waste, no LDS, no barriers.
// Epilogue: shuffle-tree reduction across the ES edge-sublanes.

template <int F>
__global__ __launch_bounds__(256) void k_agg(const _Float16* __restrict__ g,
                                             const int* __restrict__ ssrc,
                                             const int* __restrict__ rowptr,
                                             const float* __restrict__ dinv,
                                             const float* __restrict__ bias,
                                             float* __restrict__ outf,
                                             short* __restrict__ oh,
                                             short* __restrict__ ol,
                                             int relu, int writebf) {
    constexpr int F8 = F / 8;        // 16B chunks per row: 16 (F=128) or 8
    constexpr int ES = 64 / F8;      // edges per wave step: 4 or 8
    const int t = threadIdx.x;
    const int w = t >> 6, lane = t & 63;
    const int c8 = lane & (F8 - 1);
    const int es = lane / F8;
    const int n = blockIdx.x * 4 + w;
    if (n >= NNODES) return;         // wave-uniform

    const int e0 = rowptr[n], e1 = rowptr[n + 1];
    const int deg = e1 - e0;
    const int cnt = deg < 64 ? deg : 64;
    int sidx = e0 + (lane < cnt ? lane : 0);
    if (sidx >= NEDGES) sidx = NEDGES - 1;       // deg==0 tail nodes
    const int s_held = ssrc[sidx];               // edge list in registers

    const f16x8* gp = (const f16x8*)g;
    float a[8];
#pragma unroll
    for (int j = 0; j < 8; j++) a[j] = 0.f;
    if (es == 0) {                                // self term (once per chunk)
        f16x8 sv = gp[(size_t)n * F8 + c8];
#pragma unroll
        for (int j = 0; j < 8; j++) a[j] = (float)sv[j];
    }

    const int nfull = cnt / ES;                   // wave-uniform
    int k = 0;
    for (; k + 4 <= nfull; k += 4) {              // 16 edges / 4KB in flight
        int s0 = __shfl(s_held, es + (k + 0) * ES, 64);
        int s1 = __shfl(s_held, es + (k + 1) * ES, 64);
        int s2 = __shfl(s_held, es + (k + 2) * ES, 64);
        int s3 = __shfl(s_held, es + (k + 3) * ES, 64);
        f16x8 v0 = gp[(size_t)s0 * F8 + c8];
        f16x8 v1 = gp[(size_t)s1 * F8 + c8];
        f16x8 v2 = gp[(size_t)s2 * F8 + c8];
        f16x8 v3 = gp[(size_t)s3 * F8 + c8];
#pragma unroll
        for (int j = 0; j < 8; j++)
            a[j] += ((float)v0[j] + (float)v1[j]) +
                    ((float)v2[j] + (float)v3[j]);
    }
    for (; k < nfull; k++) {
        int s = __shfl(s_held, es + k * ES, 64);
        f16x8 v = gp[(size_t)s * F8 + c8];
#pragma unroll
        for (int j = 0; j < 8; j++) a[j] += (float)v[j];
    }
    {   // one partially-masked tail step; shfl issued with all lanes active
        int i = nfull * ES + es;
        int s = __shfl(s_held, i < cnt ? i : 0, 64);
        if (i < cnt) {
            f16x8 v = gp[(size_t)s * F8 + c8];
#pragma unroll
            for (int j = 0; j < 8; j++) a[j] += (float)v[j];
        }
    }
    // rare overflow (deg > 64): direct from global, es-groups split edges
    for (int e = e0 + 64 + es; e < e1; e += ES) {
        int s = ssrc[e];
        f16x8 v = gp[(size_t)s * F8 + c8];
#pragma unroll
        for (int j = 0; j < 8; j++) a[j] += (float)v[j];
    }

    // reduce across edge-sublanes (lanes differing in es)
#pragma unroll
    for (int j = 0; j < 8; j++) {
        float v = a[j];
        if (F8 == 8) v += __shfl_xor(v, 8, 64);
        v += __shfl_xor(v, 16, 64);
        v += __shfl_xor(v, 32, 64);
        a[j] = v;
    }
    if (es != 0) return;

    float dv = dinv[n];
    float o[8];
#pragma unroll
    for (int j = 0; j < 8; j++) {
        o[j] = a[j] * dv + bias[c8 * 8 + j];
        if (relu) o[j] = fmaxf(o[j], 0.f);
    }
    if (writebf) {
        short8 h8, l8;
#pragma unroll
        for (int j = 0; j < 8; j++) {
            short h, l;
            split_bf16(o[j], h, l);
            h8[j] = h; l8[j] = l;
        }
        *(short8*)&oh[(size_t)n * F + c8 * 8] = h8;
        *(short8*)&ol[(size_t)n * F + c8 * 8] = l8;
    } else {
        *(float4*)&outf[(size_t)n * F + c8 * 8] =
            make_float4(o[0], o[1], o[2], o[3]);
        *(float4*)&outf[(size_t)n * F + c8 * 8 + 4] =
            make_float4(o[4], o[5], o[6], o[7]);
    }
}

// ---------------- launch ----------------

static inline size_t align256(size_t x) { return (x + 255) & ~(size_t)255; }

extern "C" void kernel_launch(void* const* d_in, const int* in_sizes, int n_in,
                              void* d_out, int out_size, void* d_ws, size_t ws_size,
                              hipStream_t stream) {
    const float* x  = (const float*)d_in[0];
    const int*   ei = (const int*)d_in[1];
    const float* W0 = (const float*)d_in[2];
    const float* b0 = (const float*)d_in[3];
    const float* W1 = (const float*)d_in[4];
    const float* b1 = (const float*)d_in[5];
    const float* W2 = (const float*)d_in[6];
    const float* b2 = (const float*)d_in[7];
    float* out = (float*)d_out;

    const int* src = ei;
    const int* dst = ei + NEDGES;

    char* w = (char*)d_ws;
    size_t off = 0;
    float* dinv    = (float*)(w + off); off = align256(off + NNODES * 4);
    int* rowptr    = (int*)(w + off);   off = align256(off + (NNODES + 1) * 4);
    int* hist2d    = (int*)(w + off);   off = align256(off + 256 * 256 * 4);
    unsigned* buck = (unsigned*)(w + off); off = align256(off + (size_t)NEDGES * 4);
    int* ssrc      = (int*)(w + off);   off = align256(off + (size_t)NEDGES * 4);
    short* W0h     = (short*)(w + off); off = align256(off + 256 * 128 * 2);
    short* W0l     = (short*)(w + off); off = align256(off + 256 * 128 * 2);
    short* W1h     = (short*)(w + off); off = align256(off + 128 * 128 * 2);
    short* W1l     = (short*)(w + off); off = align256(off + 128 * 128 * 2);
    short* W2h     = (short*)(w + off); off = align256(off + 128 * 64 * 2);
    short* W2l     = (short*)(w + off); off = align256(off + 128 * 64 * 2);
    short* ph      = (short*)(w + off); off = align256(off + (size_t)NNODES * 128 * 2);
    short* pl      = (short*)(w + off); off = align256(off + (size_t)NNODES * 128 * 2);
    _Float16* g16  = (_Float16*)(w + off); off = align256(off + (size_t)NNODES * 128 * 2);

    const int MB = (NNODES + 63) / 64;            // 782
    const int AB = (NNODES + 3) / 4;              // 12500 (4 nodes/block, wave-per-node)

    // 1) prep: weights + coarse histogram
    k_prep<<<PREP_TOT, 256, 0, stream>>>(W0, W0h, W0l, W1, W1h, W1l,
                                         W2, W2h, W2l, dst, hist2d);
    // 2) coarse scatter (LDS-staged coalesced writes)
    k_p2<<<256, 256, 0, stream>>>(src, dst, hist2d, buck);
    // 3) finalize: rowptr/dinv/ssrc
    k_p3<<<256, 256, 0, stream>>>(buck, hist2d, rowptr, dinv, ssrc);

    // layer 0 (direct x)
    k_gemm0<<<MB, 256, 0, stream>>>(x, W0h, W0l, dinv, g16);
    k_agg<128><<<AB, 256, 0, stream>>>(g16, ssrc, rowptr, dinv, b0,
                                       (float*)nullptr, ph, pl, 1, 1);
    // layer 1
    k_gemm2<128><<<MB, 256, 0, stream>>>(ph, pl, W1h, W1l, dinv, g16, 128);
    k_agg<128><<<AB, 256, 0, stream>>>(g16, ssrc, rowptr, dinv, b1,
                                       (float*)nullptr, ph, pl, 1, 1);
    // layer 2
    k_gemm2<64><<<MB, 256, 0, stream>>>(ph, pl, W2h, W2l, dinv, g16, 128);
    k_agg<64><<<AB, 256, 0, stream>>>(g16, ssrc, rowptr, dinv, b2,
                                      out, (short*)nullptr, (short*)nullptr, 0, 0);
    (void)in_sizes; (void)n_in; (void)out_size; (void)ws_size;
}

// Round 2
// 262.145 us; speedup vs baseline: 1.0203x; 1.0203x over previous
//
#include <hip/hip_runtime.h>

#define NNODES 50000
#define NEDGES 800000
#define CHUNK 3125          // edges per CSR block (256 blocks * 3125 = 800000)

typedef __attribute__((ext_vector_type(8))) short short8;
typedef __attribute__((ext_vector_type(4))) float floatx4;
typedef __attribute__((ext_vector_type(8))) _Float16 f16x8;

// async global->LDS, 16B per lane (global_load_lds_dwordx4).
// LDS dest MUST be wave-uniform base + lane*16.
__device__ __forceinline__ void async16(const void* g, void* l) {
    __builtin_amdgcn_global_load_lds(
        (const __attribute__((address_space(1))) unsigned int*)g,
        (__attribute__((address_space(3))) unsigned int*)l, 16, 0, 0);
}

__device__ __forceinline__ void split_bf16(float v, short& hi, short& lo) {
    unsigned u = __float_as_uint(v);
    unsigned hu = u & 0xffff0000u;
    hi = (short)(hu >> 16);
    float r = v - __uint_as_float(hu);
    lo = (short)(__float_as_uint(r) >> 16);
}

// ------ prep: weight transpose/split + coarse histogram ------------------

#define PREP_WBLK 224
#define PREP_TOT  (PREP_WBLK + 256)

__global__ __launch_bounds__(256) void k_prep(
    const float* __restrict__ W0, short* __restrict__ W0h, short* __restrict__ W0l,
    const float* __restrict__ W1, short* __restrict__ W1h, short* __restrict__ W1l,
    const float* __restrict__ W2, short* __restrict__ W2h, short* __restrict__ W2l,
    const int* __restrict__ dst, int* __restrict__ hist2d,
    int* __restrict__ dhist, int* __restrict__ dcur) {
    int b = blockIdx.x, t = threadIdx.x;
    if (b < PREP_WBLK) {
        int id = b * 256 + t;
        const float* W; short *Wh, *Wl; int K, F;
        if (id < 32768) { W = W0; Wh = W0h; Wl = W0l; K = 256; F = 128; }
        else if (id < 49152) { id -= 32768; W = W1; Wh = W1h; Wl = W1l; K = 128; F = 128; }
        else if (id < 57344) { id -= 49152; W = W2; Wh = W2h; Wl = W2l; K = 128; F = 64; }
        else return;
        int f = id / K, k = id - f * K;
        short h, l;
        split_bf16(W[(size_t)k * F + f], h, l);
        Wh[id] = h;
        Wl[id] = l;
    } else {
        // per-block coarse histogram of dst>>8 (no global atomics)
        __shared__ int h[256];
        int bb = b - PREP_WBLK;
        if (bb == 0 && t < 64) { dhist[t] = 0; dcur[t] = 0; }
        h[t] = 0;
        __syncthreads();
        int e0 = bb * CHUNK;
#pragma unroll
        for (int k = 0; k < 13; k++) {
            int o = k * 256 + t;
            if (o < CHUNK) atomicAdd(&h[dst[e0 + o] >> 8], 1);
        }
        __syncthreads();
        hist2d[bb * 256 + t] = h[t];
    }
}

// P2 (self-scanning): deterministic coarse scatter, LDS-staged bucket write
// (edges placed into LDS ordered by coarse bin, then flushed with
// consecutive threads -> contiguous bursts per bin).
__global__ __launch_bounds__(256) void k_p2(const int* __restrict__ src,
                                            const int* __restrict__ dst,
                                            const int* __restrict__ hist2d,
                                            unsigned* __restrict__ buck) {
    __shared__ int ex[256], lex[256], lcur[256], delta[256];
    __shared__ unsigned lbuck[CHUNK];
    __shared__ int gd[CHUNK];
    int t = threadIdx.x, b = blockIdx.x;
    int tot = 0, pre = 0, mine = 0;
    for (int bb = 0; bb < 256; bb++) {
        int v = hist2d[bb * 256 + t];
        tot += v;
        pre += (bb < b) ? v : 0;
        if (bb == b) mine = v;
    }
    ex[t] = tot;
    lex[t] = mine;
    __syncthreads();
    for (int o = 1; o < 256; o <<= 1) {
        int x1 = (t >= o) ? ex[t - o] : 0;
        int x2 = (t >= o) ? lex[t - o] : 0;
        __syncthreads();
        ex[t] += x1;
        lex[t] += x2;
        __syncthreads();
    }
    int cur0 = (ex[t] - tot) + pre;      // global base of bin t for this block
    int lexcl = lex[t] - mine;           // local base of bin t inside block
    lcur[t] = lexcl;
    delta[t] = cur0 - lexcl;             // gaddr = delta[bin] + local_pos
    __syncthreads();
    int e0 = b * CHUNK;
#pragma unroll
    for (int k = 0; k < 13; k++) {
        int o = k * 256 + t;
        if (o < CHUNK) {
            int s = src[e0 + o], d = dst[e0 + o];
            int bin = d >> 8;
            int lp = atomicAdd(&lcur[bin], 1);   // LDS atomic only
            lbuck[lp] = (unsigned)s | ((unsigned)(d & 255) << 16);
            gd[lp] = delta[bin] + lp;
        }
    }
    __syncthreads();
#pragma unroll
    for (int k = 0; k < 13; k++) {
        int o = k * 256 + t;
        if (o < CHUNK) buck[gd[o]] = lbuck[o];
    }
}

// P3 (self-scanning): finalize coarse bin b -> rowptr/dinv/ssrc.
// NEW: also accumulate the global degree histogram (64 bins) for the
// degree-balanced agg permutation.
__global__ __launch_bounds__(256) void k_p3(const unsigned* __restrict__ buck,
                                            const int* __restrict__ hist2d,
                                            int* __restrict__ rowptr,
                                            float* __restrict__ dinv,
                                            int* __restrict__ ssrc,
                                            int* __restrict__ dhist) {
    __shared__ int ex[256], cur[256], h[256], dh[64], sS0[1], sS[1];
    int t = threadIdx.x, b = blockIdx.x;
    int tot = 0;
    for (int bb = 0; bb < 256; bb++) tot += hist2d[bb * 256 + t];
    ex[t] = tot;
    if (t < 64) dh[t] = 0;
    __syncthreads();
    for (int o = 1; o < 256; o <<= 1) {
        int xx = (t >= o) ? ex[t - o] : 0;
        __syncthreads();
        ex[t] += xx;
        __syncthreads();
    }
    if (t == b) { sS0[0] = ex[t] - tot; sS[0] = tot; }
    h[t] = 0;
    __syncthreads();
    int s0 = sS0[0], S = sS[0];
    for (int i = t; i < S; i += 256)
        atomicAdd(&h[(buck[s0 + i] >> 16) & 255], 1);
    __syncthreads();
    int v = h[t];
    ex[t] = v;
    __syncthreads();
    for (int o = 1; o < 256; o <<= 1) {
        int xx = (t >= o) ? ex[t - o] : 0;
        __syncthreads();
        ex[t] += xx;
        __syncthreads();
    }
    int excl = ex[t] - v;
    int n = b * 256 + t;
    if (n < NNODES) {
        rowptr[n] = s0 + excl;
        dinv[n] = rsqrtf((float)v + 1.0f);
        atomicAdd(&dh[v < 63 ? v : 63], 1);      // LDS degree hist
    }
    if (b == 0 && t == 0) rowptr[NNODES] = NEDGES;
    cur[t] = excl;
    __syncthreads();
    if (t < 64 && dh[t]) atomicAdd(&dhist[t], dh[t]);
    for (int i = t; i < S; i += 256) {
        unsigned pk = buck[s0 + i];
        int dl = (pk >> 16) & 255;
        int p = atomicAdd(&cur[dl], 1);
        ssrc[s0 + p] = (int)(pk & 0xFFFFu);
    }
}

// P4: degree-balanced permutation (counting sort by min(deg,63)).
// Self-scanning dbase from dhist; two-level rank (LDS + 64 global counters).
__global__ __launch_bounds__(256) void k_scat(const int* __restrict__ rowptr,
                                              const int* __restrict__ dhist,
                                              int* __restrict__ dcur,
                                              int* __restrict__ perm) {
    __shared__ int dbase[64], lhist[64], gb[64];
    int t = threadIdx.x, b = blockIdx.x;
    if (t < 64) {
        dbase[t] = dhist[t];
        lhist[t] = 0;
    }
    __syncthreads();
    for (int o = 1; o < 64; o <<= 1) {
        int x = (t >= o && t < 64) ? dbase[t - o] : 0;
        __syncthreads();
        if (t < 64) dbase[t] += x;
        __syncthreads();
    }
    int n = b * 256 + t;
    int bin = 0, lrank = 0;
    bool valid = (n < NNODES);
    if (valid) {
        int deg = rowptr[n + 1] - rowptr[n];
        bin = deg < 63 ? deg : 63;
        lrank = atomicAdd(&lhist[bin], 1);
    }
    __syncthreads();
    if (t < 64) gb[t] = lhist[t] ? atomicAdd(&dcur[t], lhist[t]) : 0;
    __syncthreads();
    if (valid) {
        int ebase = dbase[bin] - dhist[bin];     // exclusive bin base
        perm[ebase + gb[bin] + lrank] = n;
    }
}

// ------ gemm0: g16 = fp16((x @ W0) * dinv[row]) --------------------------

__global__ __launch_bounds__(256) void k_gemm0(
    const float* __restrict__ x, const short* __restrict__ Bh,
    const short* __restrict__ Bl, const float* __restrict__ dinv,
    _Float16* __restrict__ g16) {
    __shared__ __align__(16) short sAh[64 * 64], sAl[64 * 64];
    __shared__ __align__(16) short sBh[128 * 64], sBl[128 * 64];
    const int t = threadIdx.x, lane = t & 63, w = t >> 6;
    const int row0 = blockIdx.x * 64;
    const int lr = lane >> 3, lz = lane & 7;
    const int swz = (lz ^ lr) * 8;
    const int fr = lane & 15, fq = lane >> 4;
    floatx4 acc[8] = {};
    const int ar = t >> 2, ac = t & 3;
    int garow = row0 + ar;
    if (garow >= NNODES) garow = NNODES - 1;
    const float* xrow = x + (size_t)garow * 256 + ac * 16;

    for (int k0 = 0; k0 < 256; k0 += 64) {
        const float4* xp = (const float4*)(xrow + k0);
        float4 f0 = xp[0], f1 = xp[1], f2 = xp[2], f3 = xp[3];
        float va[16] = {f0.x, f0.y, f0.z, f0.w, f1.x, f1.y, f1.z, f1.w,
                        f2.x, f2.y, f2.z, f2.w, f3.x, f3.y, f3.z, f3.w};
        short8 h0, h1, l0, l1;
#pragma unroll
        for (int j = 0; j < 8; j++) {
            short h, l;
            split_bf16(va[j], h, l);     h0[j] = h; l0[j] = l;
            split_bf16(va[8 + j], h, l); h1[j] = h; l1[j] = l;
        }
        int c0 = ac * 2;
        *(short8*)&sAh[ar * 64 + ((c0 ^ (ar & 7)) * 8)] = h0;
        *(short8*)&sAh[ar * 64 + (((c0 + 1) ^ (ar & 7)) * 8)] = h1;
        *(short8*)&sAl[ar * 64 + ((c0 ^ (ar & 7)) * 8)] = l0;
        *(short8*)&sAl[ar * 64 + (((c0 + 1) ^ (ar & 7)) * 8)] = l1;
#pragma unroll
        for (int jj = 0; jj < 4; jj++) {
            int j = w * 4 + jj;
            size_t go = (size_t)(j * 8 + lr) * 256 + k0 + swz;
            async16(&Bh[go], &sBh[j * 512 + lane * 8]);
            async16(&Bl[go], &sBl[j * 512 + lane * 8]);
        }
        __syncthreads();
#pragma unroll
        for (int ks = 0; ks < 2; ks++) {
            int R = w * 16 + fr;
            int ca = ((ks * 4 + fq) ^ (R & 7)) * 8;
            short8 ah = *(const short8*)&sAh[R * 64 + ca];
            short8 al = *(const short8*)&sAl[R * 64 + ca];
#pragma unroll
            for (int nt = 0; nt < 8; nt++) {
                int n = nt * 16 + fr;
                int cb = ((ks * 4 + fq) ^ (n & 7)) * 8;
                short8 bh = *(const short8*)&sBh[n * 64 + cb];
                short8 bl = *(const short8*)&sBl[n * 64 + cb];
                acc[nt] = __builtin_amdgcn_mfma_f32_16x16x32_bf16(ah, bh, acc[nt], 0, 0, 0);
                acc[nt] = __builtin_amdgcn_mfma_f32_16x16x32_bf16(ah, bl, acc[nt], 0, 0, 0);
                acc[nt] = __builtin_amdgcn_mfma_f32_16x16x32_bf16(al, bh, acc[nt], 0, 0, 0);
            }
        }
        __syncthreads();
    }
#pragma unroll
    for (int rr = 0; rr < 4; rr++) {
        int gw = row0 + w * 16 + fq * 4 + rr;
        if (gw < NNODES) {
            float dv = dinv[gw];
#pragma unroll
            for (int nt = 0; nt < 8; nt++)
                g16[(size_t)gw * 128 + nt * 16 + fr] =
                    (_Float16)(acc[nt][rr] * dv);
        }
    }
}

// ------ gemm (layers 1/2): g16 = fp16((A @ W) * dinv), proven R8 ---------

template <int BN>
__global__ __launch_bounds__(256) void k_gemm2(
    const short* __restrict__ Ah, const short* __restrict__ Al,
    const short* __restrict__ Bh, const short* __restrict__ Bl,
    const float* __restrict__ dinv, _Float16* __restrict__ g16, int K) {
    constexpr int BM = 64, BK = 64;
    constexpr int NT = BN / 16;
    __shared__ __align__(16) short sAh[BM * BK], sAl[BM * BK];
    __shared__ __align__(16) short sBh[BN * BK], sBl[BN * BK];

    const int tid = threadIdx.x, lane = tid & 63, w = tid >> 6;
    const int row0 = blockIdx.x * BM;
    const int lr = lane >> 3;
    const int lz = lane & 7;
    const int swz = (lz ^ lr) * 8;
    const int fr = lane & 15, fq = lane >> 4;

    floatx4 acc[NT] = {};

    for (int k0 = 0; k0 < K; k0 += BK) {
#pragma unroll
        for (int jj = 0; jj < 2; jj++) {
            int j = w * 2 + jj;
            int grow = row0 + j * 8 + lr;
            if (grow >= NNODES) grow = NNODES - 1;
            size_t go = (size_t)grow * K + k0 + swz;
            async16(&Ah[go], &sAh[j * 8 * BK + lane * 8]);
            async16(&Al[go], &sAl[j * 8 * BK + lane * 8]);
        }
#pragma unroll
        for (int jj = 0; jj < BN / 32; jj++) {
            int j = w * (BN / 32) + jj;
            size_t go = (size_t)(j * 8 + lr) * K + k0 + swz;
            async16(&Bh[go], &sBh[j * 8 * BK + lane * 8]);
            async16(&Bl[go], &sBl[j * 8 * BK + lane * 8]);
        }
        __syncthreads();

#pragma unroll
        for (int ks = 0; ks < 2; ks++) {
            int R = w * 16 + fr;
            int ca = ((ks * 4 + fq) ^ (R & 7)) * 8;
            short8 ah = *(const short8*)&sAh[R * BK + ca];
            short8 al = *(const short8*)&sAl[R * BK + ca];
#pragma unroll
            for (int nt = 0; nt < NT; nt++) {
                int n = nt * 16 + fr;
                int cb = ((ks * 4 + fq) ^ (n & 7)) * 8;
                short8 bh = *(const short8*)&sBh[n * BK + cb];
                short8 bl = *(const short8*)&sBl[n * BK + cb];
                acc[nt] = __builtin_amdgcn_mfma_f32_16x16x32_bf16(ah, bh, acc[nt], 0, 0, 0);
                acc[nt] = __builtin_amdgcn_mfma_f32_16x16x32_bf16(ah, bl, acc[nt], 0, 0, 0);
                acc[nt] = __builtin_amdgcn_mfma_f32_16x16x32_bf16(al, bh, acc[nt], 0, 0, 0);
            }
        }
        __syncthreads();
    }

#pragma unroll
    for (int rr = 0; rr < 4; rr++) {
        int grow = row0 + w * 16 + fq * 4 + rr;
        if (grow < NNODES) {
            float dv = dinv[grow];
#pragma unroll
            for (int nt = 0; nt < NT; nt++)
                g16[(size_t)grow * BN + nt * 16 + fr] =
                    (_Float16)(acc[nt][rr] * dv);
        }
    }
}

// ------ Aggregation: R13 structure (proven) + degree-balanced perm -------
// F8 threads per node; edge list loaded to LDS once per node, broadcast to
// all chunk-threads. Blocks process nodes in degree-sorted order (perm) so
// all node-groups in a wave/block have identical trip counts (no max-of-4
// divergence waste, no barrier imbalance).

template <int F>
__global__ __launch_bounds__(256) void k_agg(const _Float16* __restrict__ g,
                                             const int* __restrict__ ssrc,
                                             const int* __restrict__ rowptr,
                                             const float* __restrict__ dinv,
                                             const float* __restrict__ bias,
                                             const int* __restrict__ perm,
                                             float* __restrict__ outf,
                                             short* __restrict__ oh,
                                             short* __restrict__ ol,
                                             int relu, int writebf) {
    constexpr int F8 = F / 8;          // threads per node (16 or 8)
    constexpr int NPB = 256 / F8;      // nodes per block (16 or 32)
    __shared__ int sED[NPB][64];
    int t = threadIdx.x;
    int ln = t / F8;
    int c8 = t - ln * F8;
    int idx = blockIdx.x * NPB + ln;
    bool valid = (idx < NNODES);
    int nc = valid ? perm[idx] : 0;

    int e0 = rowptr[nc], e1 = rowptr[nc + 1];
    int deg = e1 - e0;
    int cnt = deg < 64 ? deg : 64;
    for (int i = c8; i < cnt; i += F8) sED[ln][i] = ssrc[e0 + i];
    __syncthreads();

    const f16x8* gp = (const f16x8*)g;
    f16x8 sv = gp[(size_t)nc * F8 + c8];       // self term
    float a0[8], a1[8], a2[8], a3[8];
#pragma unroll
    for (int j = 0; j < 8; j++) {
        a0[j] = (float)sv[j];
        a1[j] = 0.f; a2[j] = 0.f; a3[j] = 0.f;
    }
    int i = 0;
    for (; i + 4 <= cnt; i += 4) {
        int s0 = sED[ln][i], s1 = sED[ln][i + 1];
        int s2 = sED[ln][i + 2], s3 = sED[ln][i + 3];
        f16x8 v0 = gp[(size_t)s0 * F8 + c8];
        f16x8 v1 = gp[(size_t)s1 * F8 + c8];
        f16x8 v2 = gp[(size_t)s2 * F8 + c8];
        f16x8 v3 = gp[(size_t)s3 * F8 + c8];
#pragma unroll
        for (int j = 0; j < 8; j++) {
            a0[j] += (float)v0[j];
            a1[j] += (float)v1[j];
            a2[j] += (float)v2[j];
            a3[j] += (float)v3[j];
        }
    }
    for (; i < cnt; i++) {
        int s = sED[ln][i];
        f16x8 v = gp[(size_t)s * F8 + c8];
#pragma unroll
        for (int j = 0; j < 8; j++) a0[j] += (float)v[j];
    }
    // rare overflow (deg > 64): direct from global
    for (int e = e0 + 64; e < e1; e++) {
        int s = ssrc[e];
        f16x8 v = gp[(size_t)s * F8 + c8];
#pragma unroll
        for (int j = 0; j < 8; j++) a0[j] += (float)v[j];
    }

    float dv = dinv[nc];
    float o[8];
#pragma unroll
    for (int j = 0; j < 8; j++) {
        float s = (a0[j] + a1[j]) + (a2[j] + a3[j]);
        o[j] = s * dv + bias[c8 * 8 + j];
        if (relu) o[j] = fmaxf(o[j], 0.f);
    }
    if (!valid) return;
    if (writebf) {
        short8 h8, l8;
#pragma unroll
        for (int j = 0; j < 8; j++) {
            short h, l;
            split_bf16(o[j], h, l);
            h8[j] = h; l8[j] = l;
        }
        *(short8*)&oh[(size_t)nc * F + c8 * 8] = h8;
        *(short8*)&ol[(size_t)nc * F + c8 * 8] = l8;
    } else {
        *(float4*)&outf[(size_t)nc * F + c8 * 8] =
            make_float4(o[0], o[1], o[2], o[3]);
        *(float4*)&outf[(size_t)nc * F + c8 * 8 + 4] =
            make_float4(o[4], o[5], o[6], o[7]);
    }
}

// ---------------- launch ----------------

static inline size_t align256(size_t x) { return (x + 255) & ~(size_t)255; }

extern "C" void kernel_launch(void* const* d_in, const int* in_sizes, int n_in,
                              void* d_out, int out_size, void* d_ws, size_t ws_size,
                              hipStream_t stream) {
    const float* x  = (const float*)d_in[0];
    const int*   ei = (const int*)d_in[1];
    const float* W0 = (const float*)d_in[2];
    const float* b0 = (const float*)d_in[3];
    const float* W1 = (const float*)d_in[4];
    const float* b1 = (const float*)d_in[5];
    const float* W2 = (const float*)d_in[6];
    const float* b2 = (const float*)d_in[7];
    float* out = (float*)d_out;

    const int* src = ei;
    const int* dst = ei + NEDGES;

    char* w = (char*)d_ws;
    size_t off = 0;
    float* dinv    = (float*)(w + off); off = align256(off + NNODES * 4);
    int* rowptr    = (int*)(w + off);   off = align256(off + (NNODES + 1) * 4);
    int* hist2d    = (int*)(w + off);   off = align256(off + 256 * 256 * 4);
    unsigned* buck = (unsigned*)(w + off); off = align256(off + (size_t)NEDGES * 4);
    int* ssrc      = (int*)(w + off);   off = align256(off + (size_t)NEDGES * 4);
    int* dhist     = (int*)(w + off);   off = align256(off + 64 * 4);
    int* dcur      = (int*)(w + off);   off = align256(off + 64 * 4);
    int* perm      = (int*)(w + off);   off = align256(off + NNODES * 4);
    short* W0h     = (short*)(w + off); off = align256(off + 256 * 128 * 2);
    short* W0l     = (short*)(w + off); off = align256(off + 256 * 128 * 2);
    short* W1h     = (short*)(w + off); off = align256(off + 128 * 128 * 2);
    short* W1l     = (short*)(w + off); off = align256(off + 128 * 128 * 2);
    short* W2h     = (short*)(w + off); off = align256(off + 128 * 64 * 2);
    short* W2l     = (short*)(w + off); off = align256(off + 128 * 64 * 2);
    short* ph      = (short*)(w + off); off = align256(off + (size_t)NNODES * 128 * 2);
    short* pl      = (short*)(w + off); off = align256(off + (size_t)NNODES * 128 * 2);
    _Float16* g16  = (_Float16*)(w + off); off = align256(off + (size_t)NNODES * 128 * 2);

    const int MB = (NNODES + 63) / 64;            // 782
    const int AB128 = (NNODES + 15) / 16;         // 3125 (16 nodes/block)
    const int AB64  = (NNODES + 31) / 32;         // 1563 (32 nodes/block)
    const int SB = (NNODES + 255) / 256;          // 196

    // 1) prep: weights + coarse histogram (+ zero dhist/dcur)
    k_prep<<<PREP_TOT, 256, 0, stream>>>(W0, W0h, W0l, W1, W1h, W1l,
                                         W2, W2h, W2l, dst, hist2d, dhist, dcur);
    // 2) coarse scatter (LDS-staged coalesced writes)
    k_p2<<<256, 256, 0, stream>>>(src, dst, hist2d, buck);
    // 3) finalize: rowptr/dinv/ssrc + degree histogram
    k_p3<<<256, 256, 0, stream>>>(buck, hist2d, rowptr, dinv, ssrc, dhist);
    // 4) degree-balanced permutation
    k_scat<<<SB, 256, 0, stream>>>(rowptr, dhist, dcur, perm);

    // layer 0 (direct x)
    k_gemm0<<<MB, 256, 0, stream>>>(x, W0h, W0l, dinv, g16);
    k_agg<128><<<AB128, 256, 0, stream>>>(g16, ssrc, rowptr, dinv, b0, perm,
                                          (float*)nullptr, ph, pl, 1, 1);
    // layer 1
    k_gemm2<128><<<MB, 256, 0, stream>>>(ph, pl, W1h, W1l, dinv, g16, 128);
    k_agg<128><<<AB128, 256, 0, stream>>>(g16, ssrc, rowptr, dinv, b1, perm,
                                          (float*)nullptr, ph, pl, 1, 1);
    // layer 2
    k_gemm2<64><<<MB, 256, 0, stream>>>(ph, pl, W2h, W2l, dinv, g16, 128);
    k_agg<64><<<AB64, 256, 0, stream>>>(g16, ssrc, rowptr, dinv, b2, perm,
                                        out, (short*)nullptr, (short*)nullptr, 0, 0);
    (void)in_sizes; (void)n_in; (void)out_size; (void)ws_size;
}

// Round 3
// 252.260 us; speedup vs baseline: 1.0603x; 1.0392x over previous
//
#include <hip/hip_runtime.h>

#define NNODES 50000
#define NEDGES 800000
#define CHUNK 3125          // edges per CSR block (256 blocks * 3125 = 800000)

typedef __attribute__((ext_vector_type(8))) short short8;
typedef __attribute__((ext_vector_type(4))) float floatx4;
typedef __attribute__((ext_vector_type(8))) _Float16 f16x8;

// async global->LDS, 16B per lane (global_load_lds_dwordx4).
// LDS dest MUST be wave-uniform base + lane*16.
__device__ __forceinline__ void async16(const void* g, void* l) {
    __builtin_amdgcn_global_load_lds(
        (const __attribute__((address_space(1))) unsigned int*)g,
        (__attribute__((address_space(3))) unsigned int*)l, 16, 0, 0);
}

__device__ __forceinline__ void split_bf16(float v, short& hi, short& lo) {
    unsigned u = __float_as_uint(v);
    unsigned hu = u & 0xffff0000u;
    hi = (short)(hu >> 16);
    float r = v - __uint_as_float(hu);
    lo = (short)(__float_as_uint(r) >> 16);
}

// ------ prep: weight transpose/split + coarse histogram (R0) -------------

#define PREP_WBLK 224
#define PREP_TOT  (PREP_WBLK + 256)

__global__ __launch_bounds__(256) void k_prep(
    const float* __restrict__ W0, short* __restrict__ W0h, short* __restrict__ W0l,
    const float* __restrict__ W1, short* __restrict__ W1h, short* __restrict__ W1l,
    const float* __restrict__ W2, short* __restrict__ W2h, short* __restrict__ W2l,
    const int* __restrict__ dst, int* __restrict__ hist2d) {
    int b = blockIdx.x, t = threadIdx.x;
    if (b < PREP_WBLK) {
        int id = b * 256 + t;
        const float* W; short *Wh, *Wl; int K, F;
        if (id < 32768) { W = W0; Wh = W0h; Wl = W0l; K = 256; F = 128; }
        else if (id < 49152) { id -= 32768; W = W1; Wh = W1h; Wl = W1l; K = 128; F = 128; }
        else if (id < 57344) { id -= 49152; W = W2; Wh = W2h; Wl = W2l; K = 128; F = 64; }
        else return;
        int f = id / K, k = id - f * K;
        short h, l;
        split_bf16(W[(size_t)k * F + f], h, l);
        Wh[id] = h;
        Wl[id] = l;
    } else {
        // per-block coarse histogram of dst>>8 (no global atomics)
        __shared__ int h[256];
        int bb = b - PREP_WBLK;
        h[t] = 0;
        __syncthreads();
        int e0 = bb * CHUNK;
#pragma unroll
        for (int k = 0; k < 13; k++) {
            int o = k * 256 + t;
            if (o < CHUNK) atomicAdd(&h[dst[e0 + o] >> 8], 1);
        }
        __syncthreads();
        hist2d[bb * 256 + t] = h[t];
    }
}

// P2 (self-scanning, R0): deterministic coarse scatter, LDS cursors only.
__global__ __launch_bounds__(256) void k_p2(const int* __restrict__ src,
                                            const int* __restrict__ dst,
                                            const int* __restrict__ hist2d,
                                            unsigned* __restrict__ buck) {
    __shared__ int ex[256], cur[256];
    int t = threadIdx.x, b = blockIdx.x;
    int tot = 0, pre = 0;
    for (int bb = 0; bb < 256; bb++) {
        int v = hist2d[bb * 256 + t];
        tot += v;
        pre += (bb < b) ? v : 0;
    }
    ex[t] = tot;
    __syncthreads();
    for (int o = 1; o < 256; o <<= 1) {
        int xx = (t >= o) ? ex[t - o] : 0;
        __syncthreads();
        ex[t] += xx;
        __syncthreads();
    }
    cur[t] = (ex[t] - tot) + pre;
    __syncthreads();
    int e0 = b * CHUNK;
#pragma unroll
    for (int k = 0; k < 13; k++) {
        int o = k * 256 + t;
        if (o < CHUNK) {
            int s = src[e0 + o], d = dst[e0 + o];
            int p = atomicAdd(&cur[d >> 8], 1);   // LDS atomic only
            buck[p] = (unsigned)s | ((unsigned)(d & 255) << 16);
        }
    }
}

// P3 (self-scanning, R0): finalize coarse bin b -> rowptr/dinv/ssrc.
__global__ __launch_bounds__(256) void k_p3(const unsigned* __restrict__ buck,
                                            const int* __restrict__ hist2d,
                                            int* __restrict__ rowptr,
                                            float* __restrict__ dinv,
                                            int* __restrict__ ssrc) {
    __shared__ int ex[256], cur[256], h[256], sS0[1], sS[1];
    int t = threadIdx.x, b = blockIdx.x;
    int tot = 0;
    for (int bb = 0; bb < 256; bb++) tot += hist2d[bb * 256 + t];
    ex[t] = tot;
    __syncthreads();
    for (int o = 1; o < 256; o <<= 1) {
        int xx = (t >= o) ? ex[t - o] : 0;
        __syncthreads();
        ex[t] += xx;
        __syncthreads();
    }
    if (t == b) { sS0[0] = ex[t] - tot; sS[0] = tot; }
    h[t] = 0;
    __syncthreads();
    int s0 = sS0[0], S = sS[0];
    for (int i = t; i < S; i += 256)
        atomicAdd(&h[(buck[s0 + i] >> 16) & 255], 1);
    __syncthreads();
    int v = h[t];
    ex[t] = v;
    __syncthreads();
    for (int o = 1; o < 256; o <<= 1) {
        int xx = (t >= o) ? ex[t - o] : 0;
        __syncthreads();
        ex[t] += xx;
        __syncthreads();
    }
    int excl = ex[t] - v;
    int n = b * 256 + t;
    if (n < NNODES) {
        rowptr[n] = s0 + excl;
        dinv[n] = rsqrtf((float)v + 1.0f);
    }
    if (b == 0 && t == 0) rowptr[NNODES] = NEDGES;
    cur[t] = excl;
    __syncthreads();
    for (int i = t; i < S; i += 256) {
        unsigned pk = buck[s0 + i];
        int dl = (pk >> 16) & 255;
        int p = atomicAdd(&cur[dl], 1);
        ssrc[s0 + p] = (int)(pk & 0xFFFFu);
    }
}

// ------ gemm0: g16 = fp16((x @ W0) * dinv[row]) (R0, proven) -------------

__global__ __launch_bounds__(256) void k_gemm0(
    const float* __restrict__ x, const short* __restrict__ Bh,
    const short* __restrict__ Bl, const float* __restrict__ dinv,
    _Float16* __restrict__ g16) {
    __shared__ __align__(16) short sAh[64 * 64], sAl[64 * 64];
    __shared__ __align__(16) short sBh[128 * 64], sBl[128 * 64];
    const int t = threadIdx.x, lane = t & 63, w = t >> 6;
    const int row0 = blockIdx.x * 64;
    const int lr = lane >> 3, lz = lane & 7;
    const int swz = (lz ^ lr) * 8;
    const int fr = lane & 15, fq = lane >> 4;
    floatx4 acc[8] = {};
    const int ar = t >> 2, ac = t & 3;
    int garow = row0 + ar;
    if (garow >= NNODES) garow = NNODES - 1;
    const float* xrow = x + (size_t)garow * 256 + ac * 16;

    for (int k0 = 0; k0 < 256; k0 += 64) {
        const float4* xp = (const float4*)(xrow + k0);
        float4 f0 = xp[0], f1 = xp[1], f2 = xp[2], f3 = xp[3];
        float va[16] = {f0.x, f0.y, f0.z, f0.w, f1.x, f1.y, f1.z, f1.w,
                        f2.x, f2.y, f2.z, f2.w, f3.x, f3.y, f3.z, f3.w};
        short8 h0, h1, l0, l1;
#pragma unroll
        for (int j = 0; j < 8; j++) {
            short h, l;
            split_bf16(va[j], h, l);     h0[j] = h; l0[j] = l;
            split_bf16(va[8 + j], h, l); h1[j] = h; l1[j] = l;
        }
        int c0 = ac * 2;
        *(short8*)&sAh[ar * 64 + ((c0 ^ (ar & 7)) * 8)] = h0;
        *(short8*)&sAh[ar * 64 + (((c0 + 1) ^ (ar & 7)) * 8)] = h1;
        *(short8*)&sAl[ar * 64 + ((c0 ^ (ar & 7)) * 8)] = l0;
        *(short8*)&sAl[ar * 64 + (((c0 + 1) ^ (ar & 7)) * 8)] = l1;
#pragma unroll
        for (int jj = 0; jj < 4; jj++) {
            int j = w * 4 + jj;
            size_t go = (size_t)(j * 8 + lr) * 256 + k0 + swz;
            async16(&Bh[go], &sBh[j * 512 + lane * 8]);
            async16(&Bl[go], &sBl[j * 512 + lane * 8]);
        }
        __syncthreads();
#pragma unroll
        for (int ks = 0; ks < 2; ks++) {
            int R = w * 16 + fr;
            int ca = ((ks * 4 + fq) ^ (R & 7)) * 8;
            short8 ah = *(const short8*)&sAh[R * 64 + ca];
            short8 al = *(const short8*)&sAl[R * 64 + ca];
#pragma unroll
            for (int nt = 0; nt < 8; nt++) {
                int n = nt * 16 + fr;
                int cb = ((ks * 4 + fq) ^ (n & 7)) * 8;
                short8 bh = *(const short8*)&sBh[n * 64 + cb];
                short8 bl = *(const short8*)&sBl[n * 64 + cb];
                acc[nt] = __builtin_amdgcn_mfma_f32_16x16x32_bf16(ah, bh, acc[nt], 0, 0, 0);
                acc[nt] = __builtin_amdgcn_mfma_f32_16x16x32_bf16(ah, bl, acc[nt], 0, 0, 0);
                acc[nt] = __builtin_amdgcn_mfma_f32_16x16x32_bf16(al, bh, acc[nt], 0, 0, 0);
            }
        }
        __syncthreads();
    }
#pragma unroll
    for (int rr = 0; rr < 4; rr++) {
        int gw = row0 + w * 16 + fq * 4 + rr;
        if (gw < NNODES) {
            float dv = dinv[gw];
#pragma unroll
            for (int nt = 0; nt < 8; nt++)
                g16[(size_t)gw * 128 + nt * 16 + fr] =
                    (_Float16)(acc[nt][rr] * dv);
        }
    }
}

// ------ FUSED agg(layer L) + gemm(layer L+1) -----------------------------
// Block owns BM=32 output rows. Phase A: aggregate 32 rows of gin (K=128,
// R13 gather structure: 16 threads/row, 16 rows/pass, 2 passes), apply
// dinv+bias+relu, bf16-split straight into swizzled LDS A-tile (identical
// numerics to the old ph/pl roundtrip, minus 51MB of traffic per layer).
// Phase B: [32x128] @ W -> [32xBN], x dinv[row], fp16 out (feeds next agg).

template <int BN>
__global__ __launch_bounds__(256) void k_fagg(
    const _Float16* __restrict__ gin,
    const int* __restrict__ ssrc,
    const int* __restrict__ rowptr,
    const float* __restrict__ dinv,
    const float* __restrict__ bias,
    const short* __restrict__ Bh, const short* __restrict__ Bl,
    _Float16* __restrict__ gout) {
    constexpr int BM = 32;
    constexpr int NT = BN / 32;          // col tiles per wave (4 or 2)
    __shared__ __align__(16) short sAh[2 * BM * 64], sAl[2 * BM * 64];
    __shared__ __align__(16) short sBh[BN * 64], sBl[BN * 64];
    __shared__ int sED[16][64];

    const int t = threadIdx.x, lane = t & 63, w = t >> 6;
    const int row0 = blockIdx.x * BM;

    // ---- phase A: aggregate ----
    const int ln = t >> 4;      // row within pass (0..15)
    const int c8 = t & 15;      // 16B chunk (8 halves) within the 128-row
    const f16x8* gp = (const f16x8*)gin;
#pragma unroll
    for (int p = 0; p < 2; p++) {
        int r = p * 16 + ln;
        int gr = row0 + r;
        if (gr >= NNODES) gr = NNODES - 1;
        int e0 = rowptr[gr], e1 = rowptr[gr + 1];
        int deg = e1 - e0;
        int cnt = deg < 64 ? deg : 64;
        for (int i = c8; i < cnt; i += 16) sED[ln][i] = ssrc[e0 + i];
        __syncthreads();

        f16x8 sv = gp[(size_t)gr * 16 + c8];          // self term
        float a0[8], a1[8], a2[8], a3[8];
#pragma unroll
        for (int j = 0; j < 8; j++) {
            a0[j] = (float)sv[j];
            a1[j] = 0.f; a2[j] = 0.f; a3[j] = 0.f;
        }
        int i = 0;
        for (; i + 4 <= cnt; i += 4) {
            int s0 = sED[ln][i], s1 = sED[ln][i + 1];
            int s2 = sED[ln][i + 2], s3 = sED[ln][i + 3];
            f16x8 v0 = gp[(size_t)s0 * 16 + c8];
            f16x8 v1 = gp[(size_t)s1 * 16 + c8];
            f16x8 v2 = gp[(size_t)s2 * 16 + c8];
            f16x8 v3 = gp[(size_t)s3 * 16 + c8];
#pragma unroll
            for (int j = 0; j < 8; j++) {
                a0[j] += (float)v0[j];
                a1[j] += (float)v1[j];
                a2[j] += (float)v2[j];
                a3[j] += (float)v3[j];
            }
        }
        for (; i < cnt; i++) {
            int s = sED[ln][i];
            f16x8 v = gp[(size_t)s * 16 + c8];
#pragma unroll
            for (int j = 0; j < 8; j++) a0[j] += (float)v[j];
        }
        for (int e = e0 + 64; e < e1; e++) {          // rare deg>64 overflow
            int s = ssrc[e];
            f16x8 v = gp[(size_t)s * 16 + c8];
#pragma unroll
            for (int j = 0; j < 8; j++) a0[j] += (float)v[j];
        }

        float dv = dinv[gr];
        short8 h8, l8;
#pragma unroll
        for (int j = 0; j < 8; j++) {
            float s = (a0[j] + a1[j]) + (a2[j] + a3[j]);
            float o = s * dv + bias[c8 * 8 + j];
            o = fmaxf(o, 0.f);                         // relu (both fused layers)
            short h, l;
            split_bf16(o, h, l);
            h8[j] = h; l8[j] = l;
        }
        int kt = c8 >> 3, cg = c8 & 7;
        int ao = kt * (BM * 64) + r * 64 + ((cg ^ (r & 7)) * 8);
        *(short8*)&sAh[ao] = h8;
        *(short8*)&sAl[ao] = l8;
        __syncthreads();                               // sED reuse / A-ready
    }

    // ---- phase B: gemm ----
    const int fr = lane & 15, fq = lane >> 4;
    const int lr = lane >> 3, lz = lane & 7;
    const int swz = (lz ^ lr) * 8;
    const int wr = w >> 1, wc = w & 1;
    floatx4 acc[NT] = {};
#pragma unroll
    for (int kt = 0; kt < 2; kt++) {
#pragma unroll
        for (int jj = 0; jj < BN / 32; jj++) {
            int j = w * (BN / 32) + jj;
            size_t go = (size_t)(j * 8 + lr) * 128 + kt * 64 + swz;
            async16(&Bh[go], &sBh[j * 512 + lane * 8]);
            async16(&Bl[go], &sBl[j * 512 + lane * 8]);
        }
        __syncthreads();
#pragma unroll
        for (int ks = 0; ks < 2; ks++) {
            int R = wr * 16 + fr;
            int ca = kt * (BM * 64) + R * 64 + (((ks * 4 + fq) ^ (R & 7)) * 8);
            short8 ah = *(const short8*)&sAh[ca];
            short8 al = *(const short8*)&sAl[ca];
#pragma unroll
            for (int nt = 0; nt < NT; nt++) {
                int n = wc * (BN / 2) + nt * 16 + fr;
                int cb = n * 64 + (((ks * 4 + fq) ^ (n & 7)) * 8);
                short8 bh = *(const short8*)&sBh[cb];
                short8 bl = *(const short8*)&sBl[cb];
                acc[nt] = __builtin_amdgcn_mfma_f32_16x16x32_bf16(ah, bh, acc[nt], 0, 0, 0);
                acc[nt] = __builtin_amdgcn_mfma_f32_16x16x32_bf16(ah, bl, acc[nt], 0, 0, 0);
                acc[nt] = __builtin_amdgcn_mfma_f32_16x16x32_bf16(al, bh, acc[nt], 0, 0, 0);
            }
        }
        __syncthreads();
    }

#pragma unroll
    for (int rr = 0; rr < 4; rr++) {
        int grow = row0 + wr * 16 + fq * 4 + rr;
        if (grow < NNODES) {
            float dv = dinv[grow];
#pragma unroll
            for (int nt = 0; nt < NT; nt++)
                gout[(size_t)grow * BN + wc * (BN / 2) + nt * 16 + fr] =
                    (_Float16)(acc[nt][rr] * dv);
        }
    }
}

// ------ Final aggregation (layer 2): R0 structure, fp32 out --------------

template <int F>
__global__ __launch_bounds__(256) void k_agg(const _Float16* __restrict__ g,
                                             const int* __restrict__ ssrc,
                                             const int* __restrict__ rowptr,
                                             const float* __restrict__ dinv,
                                             const float* __restrict__ bias,
                                             float* __restrict__ outf) {
    constexpr int F8 = F / 8;          // threads per node (8 for F=64)
    constexpr int NPB = 256 / F8;      // nodes per block (32)
    __shared__ int sED[NPB][64];
    int t = threadIdx.x;
    int ln = t / F8;
    int c8 = t - ln * F8;
    int n = blockIdx.x * NPB + ln;
    bool valid = (n < NNODES);
    int nc = valid ? n : NNODES - 1;

    int e0 = rowptr[nc], e1 = rowptr[nc + 1];
    int deg = e1 - e0;
    int cnt = deg < 64 ? deg : 64;
    for (int i = c8; i < cnt; i += F8) sED[ln][i] = ssrc[e0 + i];
    __syncthreads();

    const f16x8* gp = (const f16x8*)g;
    f16x8 sv = gp[(size_t)nc * F8 + c8];       // self term
    float a0[8], a1[8], a2[8], a3[8];
#pragma unroll
    for (int j = 0; j < 8; j++) {
        a0[j] = (float)sv[j];
        a1[j] = 0.f; a2[j] = 0.f; a3[j] = 0.f;
    }
    int i = 0;
    for (; i + 4 <= cnt; i += 4) {
        int s0 = sED[ln][i], s1 = sED[ln][i + 1];
        int s2 = sED[ln][i + 2], s3 = sED[ln][i + 3];
        f16x8 v0 = gp[(size_t)s0 * F8 + c8];
        f16x8 v1 = gp[(size_t)s1 * F8 + c8];
        f16x8 v2 = gp[(size_t)s2 * F8 + c8];
        f16x8 v3 = gp[(size_t)s3 * F8 + c8];
#pragma unroll
        for (int j = 0; j < 8; j++) {
            a0[j] += (float)v0[j];
            a1[j] += (float)v1[j];
            a2[j] += (float)v2[j];
            a3[j] += (float)v3[j];
        }
    }
    for (; i < cnt; i++) {
        int s = sED[ln][i];
        f16x8 v = gp[(size_t)s * F8 + c8];
#pragma unroll
        for (int j = 0; j < 8; j++) a0[j] += (float)v[j];
    }
    for (int e = e0 + 64; e < e1; e++) {
        int s = ssrc[e];
        f16x8 v = gp[(size_t)s * F8 + c8];
#pragma unroll
        for (int j = 0; j < 8; j++) a0[j] += (float)v[j];
    }

    float dv = dinv[nc];
    float o[8];
#pragma unroll
    for (int j = 0; j < 8; j++) {
        float s = (a0[j] + a1[j]) + (a2[j] + a3[j]);
        o[j] = s * dv + bias[c8 * 8 + j];
    }
    if (!valid) return;
    *(float4*)&outf[(size_t)n * F + c8 * 8] =
        make_float4(o[0], o[1], o[2], o[3]);
    *(float4*)&outf[(size_t)n * F + c8 * 8 + 4] =
        make_float4(o[4], o[5], o[6], o[7]);
}

// ---------------- launch ----------------

static inline size_t align256(size_t x) { return (x + 255) & ~(size_t)255; }

extern "C" void kernel_launch(void* const* d_in, const int* in_sizes, int n_in,
                              void* d_out, int out_size, void* d_ws, size_t ws_size,
                              hipStream_t stream) {
    const float* x  = (const float*)d_in[0];
    const int*   ei = (const int*)d_in[1];
    const float* W0 = (const float*)d_in[2];
    const float* b0 = (const float*)d_in[3];
    const float* W1 = (const float*)d_in[4];
    const float* b1 = (const float*)d_in[5];
    const float* W2 = (const float*)d_in[6];
    const float* b2 = (const float*)d_in[7];
    float* out = (float*)d_out;

    const int* src = ei;
    const int* dst = ei + NEDGES;

    char* w = (char*)d_ws;
    size_t off = 0;
    float* dinv    = (float*)(w + off); off = align256(off + NNODES * 4);
    int* rowptr    = (int*)(w + off);   off = align256(off + (NNODES + 1) * 4);
    int* hist2d    = (int*)(w + off);   off = align256(off + 256 * 256 * 4);
    unsigned* buck = (unsigned*)(w + off); off = align256(off + (size_t)NEDGES * 4);
    int* ssrc      = (int*)(w + off);   off = align256(off + (size_t)NEDGES * 4);
    short* W0h     = (short*)(w + off); off = align256(off + 256 * 128 * 2);
    short* W0l     = (short*)(w + off); off = align256(off + 256 * 128 * 2);
    short* W1h     = (short*)(w + off); off = align256(off + 128 * 128 * 2);
    short* W1l     = (short*)(w + off); off = align256(off + 128 * 128 * 2);
    short* W2h     = (short*)(w + off); off = align256(off + 128 * 64 * 2);
    short* W2l     = (short*)(w + off); off = align256(off + 128 * 64 * 2);
    _Float16* g16a = (_Float16*)(w + off); off = align256(off + (size_t)NNODES * 128 * 2);
    _Float16* g16b = (_Float16*)(w + off); off = align256(off + (size_t)NNODES * 128 * 2);
    _Float16* g16c = (_Float16*)(w + off); off = align256(off + (size_t)NNODES * 64 * 2);

    const int MB = (NNODES + 63) / 64;            // 782
    const int FB = (NNODES + 31) / 32;            // 1563 (fused, 32 rows/block)
    const int AB64 = (NNODES + 31) / 32;          // 1563 (final agg, 32 nodes/block)

    // 1) prep: weights + coarse histogram
    k_prep<<<PREP_TOT, 256, 0, stream>>>(W0, W0h, W0l, W1, W1h, W1l,
                                         W2, W2h, W2l, dst, hist2d);
    // 2) coarse scatter
    k_p2<<<256, 256, 0, stream>>>(src, dst, hist2d, buck);
    // 3) finalize: rowptr/dinv/ssrc
    k_p3<<<256, 256, 0, stream>>>(buck, hist2d, rowptr, dinv, ssrc);

    // layer 0 gemm (direct x)
    k_gemm0<<<MB, 256, 0, stream>>>(x, W0h, W0l, dinv, g16a);
    // fused: agg0 (+b0, relu) -> gemm1 -> g16b
    k_fagg<128><<<FB, 256, 0, stream>>>(g16a, ssrc, rowptr, dinv, b0,
                                        W1h, W1l, g16b);
    // fused: agg1 (+b1, relu) -> gemm2 -> g16c
    k_fagg<64><<<FB, 256, 0, stream>>>(g16b, ssrc, rowptr, dinv, b1,
                                       W2h, W2l, g16c);
    // final: agg2 (+b2, no relu) -> fp32 out
    k_agg<64><<<AB64, 256, 0, stream>>>(g16c, ssrc, rowptr, dinv, b2, out);
    (void)in_sizes; (void)n_in; (void)out_size; (void)ws_size;
}

// Round 4
// 246.054 us; speedup vs baseline: 1.0871x; 1.0252x over previous
//
#include <hip/hip_runtime.h>

#define NNODES 50000
#define NEDGES 800000
#define CHUNK 3125          // edges per CSR block (256 blocks * 3125 = 800000)

typedef __attribute__((ext_vector_type(8))) short short8;
typedef __attribute__((ext_vector_type(4))) float floatx4;
typedef __attribute__((ext_vector_type(8))) _Float16 f16x8;

// async global->LDS, 16B per lane (global_load_lds_dwordx4).
// LDS dest MUST be wave-uniform base + lane*16.
__device__ __forceinline__ void async16(const void* g, void* l) {
    __builtin_amdgcn_global_load_lds(
        (const __attribute__((address_space(1))) unsigned int*)g,
        (__attribute__((address_space(3))) unsigned int*)l, 16, 0, 0);
}

__device__ __forceinline__ void split_bf16(float v, short& hi, short& lo) {
    unsigned u = __float_as_uint(v);
    unsigned hu = u & 0xffff0000u;
    hi = (short)(hu >> 16);
    float r = v - __uint_as_float(hu);
    lo = (short)(__float_as_uint(r) >> 16);
}

// ------ prep: weight transpose/split + coarse histogram (R0) -------------

#define PREP_WBLK 224
#define PREP_TOT  (PREP_WBLK + 256)

__global__ __launch_bounds__(256) void k_prep(
    const float* __restrict__ W0, short* __restrict__ W0h, short* __restrict__ W0l,
    const float* __restrict__ W1, short* __restrict__ W1h, short* __restrict__ W1l,
    const float* __restrict__ W2, short* __restrict__ W2h, short* __restrict__ W2l,
    const int* __restrict__ dst, int* __restrict__ hist2d) {
    int b = blockIdx.x, t = threadIdx.x;
    if (b < PREP_WBLK) {
        int id = b * 256 + t;
        const float* W; short *Wh, *Wl; int K, F;
        if (id < 32768) { W = W0; Wh = W0h; Wl = W0l; K = 256; F = 128; }
        else if (id < 49152) { id -= 32768; W = W1; Wh = W1h; Wl = W1l; K = 128; F = 128; }
        else if (id < 57344) { id -= 49152; W = W2; Wh = W2h; Wl = W2l; K = 128; F = 64; }
        else return;
        int f = id / K, k = id - f * K;
        short h, l;
        split_bf16(W[(size_t)k * F + f], h, l);
        Wh[id] = h;
        Wl[id] = l;
    } else {
        // per-block coarse histogram of dst>>8 (no global atomics)
        __shared__ int h[256];
        int bb = b - PREP_WBLK;
        h[t] = 0;
        __syncthreads();
        int e0 = bb * CHUNK;
#pragma unroll
        for (int k = 0; k < 13; k++) {
            int o = k * 256 + t;
            if (o < CHUNK) atomicAdd(&h[dst[e0 + o] >> 8], 1);
        }
        __syncthreads();
        hist2d[bb * 256 + t] = h[t];
    }
}

// P2 (self-scanning, R0): deterministic coarse scatter, LDS cursors only.
__global__ __launch_bounds__(256) void k_p2(const int* __restrict__ src,
                                            const int* __restrict__ dst,
                                            const int* __restrict__ hist2d,
                                            unsigned* __restrict__ buck) {
    __shared__ int ex[256], cur[256];
    int t = threadIdx.x, b = blockIdx.x;
    int tot = 0, pre = 0;
    for (int bb = 0; bb < 256; bb++) {
        int v = hist2d[bb * 256 + t];
        tot += v;
        pre += (bb < b) ? v : 0;
    }
    ex[t] = tot;
    __syncthreads();
    for (int o = 1; o < 256; o <<= 1) {
        int xx = (t >= o) ? ex[t - o] : 0;
        __syncthreads();
        ex[t] += xx;
        __syncthreads();
    }
    cur[t] = (ex[t] - tot) + pre;
    __syncthreads();
    int e0 = b * CHUNK;
#pragma unroll
    for (int k = 0; k < 13; k++) {
        int o = k * 256 + t;
        if (o < CHUNK) {
            int s = src[e0 + o], d = dst[e0 + o];
            int p = atomicAdd(&cur[d >> 8], 1);   // LDS atomic only
            buck[p] = (unsigned)s | ((unsigned)(d & 255) << 16);
        }
    }
}

// P3 (self-scanning, R0): finalize coarse bin b -> rowptr/dinv/ssrc.
__global__ __launch_bounds__(256) void k_p3(const unsigned* __restrict__ buck,
                                            const int* __restrict__ hist2d,
                                            int* __restrict__ rowptr,
                                            float* __restrict__ dinv,
                                            int* __restrict__ ssrc) {
    __shared__ int ex[256], cur[256], h[256], sS0[1], sS[1];
    int t = threadIdx.x, b = blockIdx.x;
    int tot = 0;
    for (int bb = 0; bb < 256; bb++) tot += hist2d[bb * 256 + t];
    ex[t] = tot;
    __syncthreads();
    for (int o = 1; o < 256; o <<= 1) {
        int xx = (t >= o) ? ex[t - o] : 0;
        __syncthreads();
        ex[t] += xx;
        __syncthreads();
    }
    if (t == b) { sS0[0] = ex[t] - tot; sS[0] = tot; }
    h[t] = 0;
    __syncthreads();
    int s0 = sS0[0], S = sS[0];
    for (int i = t; i < S; i += 256)
        atomicAdd(&h[(buck[s0 + i] >> 16) & 255], 1);
    __syncthreads();
    int v = h[t];
    ex[t] = v;
    __syncthreads();
    for (int o = 1; o < 256; o <<= 1) {
        int xx = (t >= o) ? ex[t - o] : 0;
        __syncthreads();
        ex[t] += xx;
        __syncthreads();
    }
    int excl = ex[t] - v;
    int n = b * 256 + t;
    if (n < NNODES) {
        rowptr[n] = s0 + excl;
        dinv[n] = rsqrtf((float)v + 1.0f);
    }
    if (b == 0 && t == 0) rowptr[NNODES] = NEDGES;
    cur[t] = excl;
    __syncthreads();
    for (int i = t; i < S; i += 256) {
        unsigned pk = buck[s0 + i];
        int dl = (pk >> 16) & 255;
        int p = atomicAdd(&cur[dl], 1);
        ssrc[s0 + p] = (int)(pk & 0xFFFFu);
    }
}

// ------ gemm0: g16 = fp16((x @ W0) * dinv[row]) (R0, proven) -------------

__global__ __launch_bounds__(256) void k_gemm0(
    const float* __restrict__ x, const short* __restrict__ Bh,
    const short* __restrict__ Bl, const float* __restrict__ dinv,
    _Float16* __restrict__ g16) {
    __shared__ __align__(16) short sAh[64 * 64], sAl[64 * 64];
    __shared__ __align__(16) short sBh[128 * 64], sBl[128 * 64];
    const int t = threadIdx.x, lane = t & 63, w = t >> 6;
    const int row0 = blockIdx.x * 64;
    const int lr = lane >> 3, lz = lane & 7;
    const int swz = (lz ^ lr) * 8;
    const int fr = lane & 15, fq = lane >> 4;
    floatx4 acc[8] = {};
    const int ar = t >> 2, ac = t & 3;
    int garow = row0 + ar;
    if (garow >= NNODES) garow = NNODES - 1;
    const float* xrow = x + (size_t)garow * 256 + ac * 16;

    for (int k0 = 0; k0 < 256; k0 += 64) {
        const float4* xp = (const float4*)(xrow + k0);
        float4 f0 = xp[0], f1 = xp[1], f2 = xp[2], f3 = xp[3];
        float va[16] = {f0.x, f0.y, f0.z, f0.w, f1.x, f1.y, f1.z, f1.w,
                        f2.x, f2.y, f2.z, f2.w, f3.x, f3.y, f3.z, f3.w};
        short8 h0, h1, l0, l1;
#pragma unroll
        for (int j = 0; j < 8; j++) {
            short h, l;
            split_bf16(va[j], h, l);     h0[j] = h; l0[j] = l;
            split_bf16(va[8 + j], h, l); h1[j] = h; l1[j] = l;
        }
        int c0 = ac * 2;
        *(short8*)&sAh[ar * 64 + ((c0 ^ (ar & 7)) * 8)] = h0;
        *(short8*)&sAh[ar * 64 + (((c0 + 1) ^ (ar & 7)) * 8)] = h1;
        *(short8*)&sAl[ar * 64 + ((c0 ^ (ar & 7)) * 8)] = l0;
        *(short8*)&sAl[ar * 64 + (((c0 + 1) ^ (ar & 7)) * 8)] = l1;
#pragma unroll
        for (int jj = 0; jj < 4; jj++) {
            int j = w * 4 + jj;
            size_t go = (size_t)(j * 8 + lr) * 256 + k0 + swz;
            async16(&Bh[go], &sBh[j * 512 + lane * 8]);
            async16(&Bl[go], &sBl[j * 512 + lane * 8]);
        }
        __syncthreads();
#pragma unroll
        for (int ks = 0; ks < 2; ks++) {
            int R = w * 16 + fr;
            int ca = ((ks * 4 + fq) ^ (R & 7)) * 8;
            short8 ah = *(const short8*)&sAh[R * 64 + ca];
            short8 al = *(const short8*)&sAl[R * 64 + ca];
#pragma unroll
            for (int nt = 0; nt < 8; nt++) {
                int n = nt * 16 + fr;
                int cb = ((ks * 4 + fq) ^ (n & 7)) * 8;
                short8 bh = *(const short8*)&sBh[n * 64 + cb];
                short8 bl = *(const short8*)&sBl[n * 64 + cb];
                acc[nt] = __builtin_amdgcn_mfma_f32_16x16x32_bf16(ah, bh, acc[nt], 0, 0, 0);
                acc[nt] = __builtin_amdgcn_mfma_f32_16x16x32_bf16(ah, bl, acc[nt], 0, 0, 0);
                acc[nt] = __builtin_amdgcn_mfma_f32_16x16x32_bf16(al, bh, acc[nt], 0, 0, 0);
            }
        }
        __syncthreads();
    }
#pragma unroll
    for (int rr = 0; rr < 4; rr++) {
        int gw = row0 + w * 16 + fq * 4 + rr;
        if (gw < NNODES) {
            float dv = dinv[gw];
#pragma unroll
            for (int nt = 0; nt < 8; nt++)
                g16[(size_t)gw * 128 + nt * 16 + fr] =
                    (_Float16)(acc[nt][rr] * dv);
        }
    }
}

// ------ FUSED agg(layer L) + gemm(layer L+1) -----------------------------
// R4: LDS 52KB -> 32KB (3 -> 5 blocks/CU) to fix the latency-bound gather
// phase (R3 counters: Occ 23%, MfmaUtil 3.7%, hbm 25% -> nothing saturated).
//  - sED (phase A only) unioned with the B-tile region (phase B only).
//  - BN=128: B staged one half at a time (16KB buffer), 2-pass MFMA
//    (ah*bh+al*bh, then ah*bl). BN=64: full B tile fits the 16KB union.

template <int BN>
__global__ __launch_bounds__(256) void k_fagg(
    const _Float16* __restrict__ gin,
    const int* __restrict__ ssrc,
    const int* __restrict__ rowptr,
    const float* __restrict__ dinv,
    const float* __restrict__ bias,
    const short* __restrict__ Bh, const short* __restrict__ Bl,
    _Float16* __restrict__ gout) {
    constexpr int BM = 32;
    constexpr int NT = BN / 32;          // col tiles per wave (4 or 2)
    __shared__ __align__(16) short sAh[2 * BM * 64], sAl[2 * BM * 64]; // 8+8 KB
    __shared__ __align__(16) char uB[16384];                          // 16 KB union

    const int t = threadIdx.x, lane = t & 63, w = t >> 6;
    const int row0 = blockIdx.x * BM;

    // ---- phase A: aggregate (sED aliases uB) ----
    int (*sED)[64] = (int(*)[64])uB;    // 16 x 64 ints = 4KB
    const int ln = t >> 4;      // row within pass (0..15)
    const int c8 = t & 15;      // 16B chunk (8 halves) within the 128-row
    const f16x8* gp = (const f16x8*)gin;
#pragma unroll
    for (int p = 0; p < 2; p++) {
        int r = p * 16 + ln;
        int gr = row0 + r;
        if (gr >= NNODES) gr = NNODES - 1;
        int e0 = rowptr[gr], e1 = rowptr[gr + 1];
        int deg = e1 - e0;
        int cnt = deg < 64 ? deg : 64;
        for (int i = c8; i < cnt; i += 16) sED[ln][i] = ssrc[e0 + i];
        __syncthreads();

        f16x8 sv = gp[(size_t)gr * 16 + c8];          // self term
        float a0[8], a1[8], a2[8], a3[8];
#pragma unroll
        for (int j = 0; j < 8; j++) {
            a0[j] = (float)sv[j];
            a1[j] = 0.f; a2[j] = 0.f; a3[j] = 0.f;
        }
        int i = 0;
        for (; i + 4 <= cnt; i += 4) {
            int s0 = sED[ln][i], s1 = sED[ln][i + 1];
            int s2 = sED[ln][i + 2], s3 = sED[ln][i + 3];
            f16x8 v0 = gp[(size_t)s0 * 16 + c8];
            f16x8 v1 = gp[(size_t)s1 * 16 + c8];
            f16x8 v2 = gp[(size_t)s2 * 16 + c8];
            f16x8 v3 = gp[(size_t)s3 * 16 + c8];
#pragma unroll
            for (int j = 0; j < 8; j++) {
                a0[j] += (float)v0[j];
                a1[j] += (float)v1[j];
                a2[j] += (float)v2[j];
                a3[j] += (float)v3[j];
            }
        }
        for (; i < cnt; i++) {
            int s = sED[ln][i];
            f16x8 v = gp[(size_t)s * 16 + c8];
#pragma unroll
            for (int j = 0; j < 8; j++) a0[j] += (float)v[j];
        }
        for (int e = e0 + 64; e < e1; e++) {          // rare deg>64 overflow
            int s = ssrc[e];
            f16x8 v = gp[(size_t)s * 16 + c8];
#pragma unroll
            for (int j = 0; j < 8; j++) a0[j] += (float)v[j];
        }

        float dv = dinv[gr];
        short8 h8, l8;
#pragma unroll
        for (int j = 0; j < 8; j++) {
            float s = (a0[j] + a1[j]) + (a2[j] + a3[j]);
            float o = s * dv + bias[c8 * 8 + j];
            o = fmaxf(o, 0.f);                         // relu (both fused layers)
            short h, l;
            split_bf16(o, h, l);
            h8[j] = h; l8[j] = l;
        }
        int kt = c8 >> 3, cg = c8 & 7;
        int ao = kt * (BM * 64) + r * 64 + ((cg ^ (r & 7)) * 8);
        *(short8*)&sAh[ao] = h8;
        *(short8*)&sAl[ao] = l8;
        __syncthreads();                               // sED reuse / A-ready
    }

    // ---- phase B: gemm ----
    const int fr = lane & 15, fq = lane >> 4;
    const int lr = lane >> 3, lz = lane & 7;
    const int swz = (lz ^ lr) * 8;
    const int wr = w >> 1, wc = w & 1;
    floatx4 acc[NT] = {};

    if constexpr (BN == 128) {
        short* sB = (short*)uB;                        // one half: 128*64*2B = 16KB
#pragma unroll
        for (int kt = 0; kt < 2; kt++) {
            // stage H half
#pragma unroll
            for (int jj = 0; jj < 4; jj++) {
                int j = w * 4 + jj;
                size_t go = (size_t)(j * 8 + lr) * 128 + kt * 64 + swz;
                async16(&Bh[go], &sB[j * 512 + lane * 8]);
            }
            __syncthreads();
#pragma unroll
            for (int ks = 0; ks < 2; ks++) {
                int R = wr * 16 + fr;
                int ca = kt * (BM * 64) + R * 64 + (((ks * 4 + fq) ^ (R & 7)) * 8);
                short8 ah = *(const short8*)&sAh[ca];
                short8 al = *(const short8*)&sAl[ca];
#pragma unroll
                for (int nt = 0; nt < NT; nt++) {
                    int n = wc * (BN / 2) + nt * 16 + fr;
                    int cb = n * 64 + (((ks * 4 + fq) ^ (n & 7)) * 8);
                    short8 bh = *(const short8*)&sB[cb];
                    acc[nt] = __builtin_amdgcn_mfma_f32_16x16x32_bf16(ah, bh, acc[nt], 0, 0, 0);
                    acc[nt] = __builtin_amdgcn_mfma_f32_16x16x32_bf16(al, bh, acc[nt], 0, 0, 0);
                }
            }
            __syncthreads();
            // stage L half (same buffer)
#pragma unroll
            for (int jj = 0; jj < 4; jj++) {
                int j = w * 4 + jj;
                size_t go = (size_t)(j * 8 + lr) * 128 + kt * 64 + swz;
                async16(&Bl[go], &sB[j * 512 + lane * 8]);
            }
            __syncthreads();
#pragma unroll
            for (int ks = 0; ks < 2; ks++) {
                int R = wr * 16 + fr;
                int ca = kt * (BM * 64) + R * 64 + (((ks * 4 + fq) ^ (R & 7)) * 8);
                short8 ah = *(const short8*)&sAh[ca];
#pragma unroll
                for (int nt = 0; nt < NT; nt++) {
                    int n = wc * (BN / 2) + nt * 16 + fr;
                    int cb = n * 64 + (((ks * 4 + fq) ^ (n & 7)) * 8);
                    short8 bl = *(const short8*)&sB[cb];
                    acc[nt] = __builtin_amdgcn_mfma_f32_16x16x32_bf16(ah, bl, acc[nt], 0, 0, 0);
                }
            }
            __syncthreads();
        }
    } else {
        short* sBh_ = (short*)uB;                      // 64*64*2B = 8KB
        short* sBl_ = (short*)uB + 64 * 64;            // 8KB
#pragma unroll
        for (int kt = 0; kt < 2; kt++) {
#pragma unroll
            for (int jj = 0; jj < 2; jj++) {
                int j = w * 2 + jj;
                size_t go = (size_t)(j * 8 + lr) * 128 + kt * 64 + swz;
                async16(&Bh[go], &sBh_[j * 512 + lane * 8]);
                async16(&Bl[go], &sBl_[j * 512 + lane * 8]);
            }
            __syncthreads();
#pragma unroll
            for (int ks = 0; ks < 2; ks++) {
                int R = wr * 16 + fr;
                int ca = kt * (BM * 64) + R * 64 + (((ks * 4 + fq) ^ (R & 7)) * 8);
                short8 ah = *(const short8*)&sAh[ca];
                short8 al = *(const short8*)&sAl[ca];
#pragma unroll
                for (int nt = 0; nt < NT; nt++) {
                    int n = wc * (BN / 2) + nt * 16 + fr;
                    int cb = n * 64 + (((ks * 4 + fq) ^ (n & 7)) * 8);
                    short8 bh = *(const short8*)&sBh_[cb];
                    short8 bl = *(const short8*)&sBl_[cb];
                    acc[nt] = __builtin_amdgcn_mfma_f32_16x16x32_bf16(ah, bh, acc[nt], 0, 0, 0);
                    acc[nt] = __builtin_amdgcn_mfma_f32_16x16x32_bf16(ah, bl, acc[nt], 0, 0, 0);
                    acc[nt] = __builtin_amdgcn_mfma_f32_16x16x32_bf16(al, bh, acc[nt], 0, 0, 0);
                }
            }
            __syncthreads();
        }
    }

#pragma unroll
    for (int rr = 0; rr < 4; rr++) {
        int grow = row0 + wr * 16 + fq * 4 + rr;
        if (grow < NNODES) {
            float dv = dinv[grow];
#pragma unroll
            for (int nt = 0; nt < NT; nt++)
                gout[(size_t)grow * BN + wc * (BN / 2) + nt * 16 + fr] =
                    (_Float16)(acc[nt][rr] * dv);
        }
    }
}

// ------ Final aggregation (layer 2): R0 structure, fp32 out --------------

template <int F>
__global__ __launch_bounds__(256) void k_agg(const _Float16* __restrict__ g,
                                             const int* __restrict__ ssrc,
                                             const int* __restrict__ rowptr,
                                             const float* __restrict__ dinv,
                                             const float* __restrict__ bias,
                                             float* __restrict__ outf) {
    constexpr int F8 = F / 8;          // threads per node (8 for F=64)
    constexpr int NPB = 256 / F8;      // nodes per block (32)
    __shared__ int sED[NPB][64];
    int t = threadIdx.x;
    int ln = t / F8;
    int c8 = t - ln * F8;
    int n = blockIdx.x * NPB + ln;
    bool valid = (n < NNODES);
    int nc = valid ? n : NNODES - 1;

    int e0 = rowptr[nc], e1 = rowptr[nc + 1];
    int deg = e1 - e0;
    int cnt = deg < 64 ? deg : 64;
    for (int i = c8; i < cnt; i += F8) sED[ln][i] = ssrc[e0 + i];
    __syncthreads();

    const f16x8* gp = (const f16x8*)g;
    f16x8 sv = gp[(size_t)nc * F8 + c8];       // self term
    float a0[8], a1[8], a2[8], a3[8];
#pragma unroll
    for (int j = 0; j < 8; j++) {
        a0[j] = (float)sv[j];
        a1[j] = 0.f; a2[j] = 0.f; a3[j] = 0.f;
    }
    int i = 0;
    for (; i + 4 <= cnt; i += 4) {
        int s0 = sED[ln][i], s1 = sED[ln][i + 1];
        int s2 = sED[ln][i + 2], s3 = sED[ln][i + 3];
        f16x8 v0 = gp[(size_t)s0 * F8 + c8];
        f16x8 v1 = gp[(size_t)s1 * F8 + c8];
        f16x8 v2 = gp[(size_t)s2 * F8 + c8];
        f16x8 v3 = gp[(size_t)s3 * F8 + c8];
#pragma unroll
        for (int j = 0; j < 8; j++) {
            a0[j] += (float)v0[j];
            a1[j] += (float)v1[j];
            a2[j] += (float)v2[j];
            a3[j] += (float)v3[j];
        }
    }
    for (; i < cnt; i++) {
        int s = sED[ln][i];
        f16x8 v = gp[(size_t)s * F8 + c8];
#pragma unroll
        for (int j = 0; j < 8; j++) a0[j] += (float)v[j];
    }
    for (int e = e0 + 64; e < e1; e++) {
        int s = ssrc[e];
        f16x8 v = gp[(size_t)s * F8 + c8];
#pragma unroll
        for (int j = 0; j < 8; j++) a0[j] += (float)v[j];
    }

    float dv = dinv[nc];
    float o[8];
#pragma unroll
    for (int j = 0; j < 8; j++) {
        float s = (a0[j] + a1[j]) + (a2[j] + a3[j]);
        o[j] = s * dv + bias[c8 * 8 + j];
    }
    if (!valid) return;
    *(float4*)&outf[(size_t)n * F + c8 * 8] =
        make_float4(o[0], o[1], o[2], o[3]);
    *(float4*)&outf[(size_t)n * F + c8 * 8 + 4] =
        make_float4(o[4], o[5], o[6], o[7]);
}

// ---------------- launch ----------------

static inline size_t align256(size_t x) { return (x + 255) & ~(size_t)255; }

extern "C" void kernel_launch(void* const* d_in, const int* in_sizes, int n_in,
                              void* d_out, int out_size, void* d_ws, size_t ws_size,
                              hipStream_t stream) {
    const float* x  = (const float*)d_in[0];
    const int*   ei = (const int*)d_in[1];
    const float* W0 = (const float*)d_in[2];
    const float* b0 = (const float*)d_in[3];
    const float* W1 = (const float*)d_in[4];
    const float* b1 = (const float*)d_in[5];
    const float* W2 = (const float*)d_in[6];
    const float* b2 = (const float*)d_in[7];
    float* out = (float*)d_out;

    const int* src = ei;
    const int* dst = ei + NEDGES;

    char* w = (char*)d_ws;
    size_t off = 0;
    float* dinv    = (float*)(w + off); off = align256(off + NNODES * 4);
    int* rowptr    = (int*)(w + off);   off = align256(off + (NNODES + 1) * 4);
    int* hist2d    = (int*)(w + off);   off = align256(off + 256 * 256 * 4);
    unsigned* buck = (unsigned*)(w + off); off = align256(off + (size_t)NEDGES * 4);
    int* ssrc      = (int*)(w + off);   off = align256(off + (size_t)NEDGES * 4);
    short* W0h     = (short*)(w + off); off = align256(off + 256 * 128 * 2);
    short* W0l     = (short*)(w + off); off = align256(off + 256 * 128 * 2);
    short* W1h     = (short*)(w + off); off = align256(off + 128 * 128 * 2);
    short* W1l     = (short*)(w + off); off = align256(off + 128 * 128 * 2);
    short* W2h     = (short*)(w + off); off = align256(off + 128 * 64 * 2);
    short* W2l     = (short*)(w + off); off = align256(off + 128 * 64 * 2);
    _Float16* g16a = (_Float16*)(w + off); off = align256(off + (size_t)NNODES * 128 * 2);
    _Float16* g16b = (_Float16*)(w + off); off = align256(off + (size_t)NNODES * 128 * 2);
    _Float16* g16c = (_Float16*)(w + off); off = align256(off + (size_t)NNODES * 64 * 2);

    const int MB = (NNODES + 63) / 64;            // 782
    const int FB = (NNODES + 31) / 32;            // 1563 (fused, 32 rows/block)
    const int AB64 = (NNODES + 31) / 32;          // 1563 (final agg, 32 nodes/block)

    // 1) prep: weights + coarse histogram
    k_prep<<<PREP_TOT, 256, 0, stream>>>(W0, W0h, W0l, W1, W1h, W1l,
                                         W2, W2h, W2l, dst, hist2d);
    // 2) coarse scatter
    k_p2<<<256, 256, 0, stream>>>(src, dst, hist2d, buck);
    // 3) finalize: rowptr/dinv/ssrc
    k_p3<<<256, 256, 0, stream>>>(buck, hist2d, rowptr, dinv, ssrc);

    // layer 0 gemm (direct x)
    k_gemm0<<<MB, 256, 0, stream>>>(x, W0h, W0l, dinv, g16a);
    // fused: agg0 (+b0, relu) -> gemm1 -> g16b
    k_fagg<128><<<FB, 256, 0, stream>>>(g16a, ssrc, rowptr, dinv, b0,
                                        W1h, W1l, g16b);
    // fused: agg1 (+b1, relu) -> gemm2 -> g16c
    k_fagg<64><<<FB, 256, 0, stream>>>(g16b, ssrc, rowptr, dinv, b1,
                                       W2h, W2l, g16c);
    // final: agg2 (+b2, no relu) -> fp32 out
    k_agg<64><<<AB64, 256, 0, stream>>>(g16c, ssrc, rowptr, dinv, b2, out);
    (void)in_sizes; (void)n_in; (void)out_size; (void)ws_size;
}

// Round 5
// 239.629 us; speedup vs baseline: 1.1162x; 1.0268x over previous
//
#include <hip/hip_runtime.h>

#define NNODES 50000
#define NEDGES 800000
#define CHUNK 3125          // edges per CSR block (256 blocks * 3125 = 800000)

typedef __attribute__((ext_vector_type(8))) short short8;
typedef __attribute__((ext_vector_type(4))) float floatx4;
typedef __attribute__((ext_vector_type(8))) _Float16 f16x8;

// async global->LDS, 16B per lane (global_load_lds_dwordx4).
// LDS dest MUST be wave-uniform base + lane*16.
__device__ __forceinline__ void async16(const void* g, void* l) {
    __builtin_amdgcn_global_load_lds(
        (const __attribute__((address_space(1))) unsigned int*)g,
        (__attribute__((address_space(3))) unsigned int*)l, 16, 0, 0);
}

__device__ __forceinline__ void split_bf16(float v, short& hi, short& lo) {
    unsigned u = __float_as_uint(v);
    unsigned hu = u & 0xffff0000u;
    hi = (short)(hu >> 16);
    float r = v - __uint_as_float(hu);
    lo = (short)(__float_as_uint(r) >> 16);
}

// ------ prep: weight transpose/split + coarse histogram (R0) -------------

#define PREP_WBLK 224
#define PREP_TOT  (PREP_WBLK + 256)

__global__ __launch_bounds__(256) void k_prep(
    const float* __restrict__ W0, short* __restrict__ W0h, short* __restrict__ W0l,
    const float* __restrict__ W1, short* __restrict__ W1h, short* __restrict__ W1l,
    const float* __restrict__ W2, short* __restrict__ W2h, short* __restrict__ W2l,
    const int* __restrict__ dst, int* __restrict__ hist2d) {
    int b = blockIdx.x, t = threadIdx.x;
    if (b < PREP_WBLK) {
        int id = b * 256 + t;
        const float* W; short *Wh, *Wl; int K, F;
        if (id < 32768) { W = W0; Wh = W0h; Wl = W0l; K = 256; F = 128; }
        else if (id < 49152) { id -= 32768; W = W1; Wh = W1h; Wl = W1l; K = 128; F = 128; }
        else if (id < 57344) { id -= 49152; W = W2; Wh = W2h; Wl = W2l; K = 128; F = 64; }
        else return;
        int f = id / K, k = id - f * K;
        short h, l;
        split_bf16(W[(size_t)k * F + f], h, l);
        Wh[id] = h;
        Wl[id] = l;
    } else {
        // per-block coarse histogram of dst>>8 (no global atomics)
        __shared__ int h[256];
        int bb = b - PREP_WBLK;
        h[t] = 0;
        __syncthreads();
        int e0 = bb * CHUNK;
#pragma unroll
        for (int k = 0; k < 13; k++) {
            int o = k * 256 + t;
            if (o < CHUNK) atomicAdd(&h[dst[e0 + o] >> 8], 1);
        }
        __syncthreads();
        hist2d[bb * 256 + t] = h[t];
    }
}

// P2 (self-scanning, R0): deterministic coarse scatter, LDS cursors only.
__global__ __launch_bounds__(256) void k_p2(const int* __restrict__ src,
                                            const int* __restrict__ dst,
                                            const int* __restrict__ hist2d,
                                            unsigned* __restrict__ buck) {
    __shared__ int ex[256], cur[256];
    int t = threadIdx.x, b = blockIdx.x;
    int tot = 0, pre = 0;
    for (int bb = 0; bb < 256; bb++) {
        int v = hist2d[bb * 256 + t];
        tot += v;
        pre += (bb < b) ? v : 0;
    }
    ex[t] = tot;
    __syncthreads();
    for (int o = 1; o < 256; o <<= 1) {
        int xx = (t >= o) ? ex[t - o] : 0;
        __syncthreads();
        ex[t] += xx;
        __syncthreads();
    }
    cur[t] = (ex[t] - tot) + pre;
    __syncthreads();
    int e0 = b * CHUNK;
#pragma unroll
    for (int k = 0; k < 13; k++) {
        int o = k * 256 + t;
        if (o < CHUNK) {
            int s = src[e0 + o], d = dst[e0 + o];
            int p = atomicAdd(&cur[d >> 8], 1);   // LDS atomic only
            buck[p] = (unsigned)s | ((unsigned)(d & 255) << 16);
        }
    }
}

// P3 (self-scanning, R0): finalize coarse bin b -> rowptr/dinv/ssrc.
__global__ __launch_bounds__(256) void k_p3(const unsigned* __restrict__ buck,
                                            const int* __restrict__ hist2d,
                                            int* __restrict__ rowptr,
                                            float* __restrict__ dinv,
                                            int* __restrict__ ssrc) {
    __shared__ int ex[256], cur[256], h[256], sS0[1], sS[1];
    int t = threadIdx.x, b = blockIdx.x;
    int tot = 0;
    for (int bb = 0; bb < 256; bb++) tot += hist2d[bb * 256 + t];
    ex[t] = tot;
    __syncthreads();
    for (int o = 1; o < 256; o <<= 1) {
        int xx = (t >= o) ? ex[t - o] : 0;
        __syncthreads();
        ex[t] += xx;
        __syncthreads();
    }
    if (t == b) { sS0[0] = ex[t] - tot; sS[0] = tot; }
    h[t] = 0;
    __syncthreads();
    int s0 = sS0[0], S = sS[0];
    for (int i = t; i < S; i += 256)
        atomicAdd(&h[(buck[s0 + i] >> 16) & 255], 1);
    __syncthreads();
    int v = h[t];
    ex[t] = v;
    __syncthreads();
    for (int o = 1; o < 256; o <<= 1) {
        int xx = (t >= o) ? ex[t - o] : 0;
        __syncthreads();
        ex[t] += xx;
        __syncthreads();
    }
    int excl = ex[t] - v;
    int n = b * 256 + t;
    if (n < NNODES) {
        rowptr[n] = s0 + excl;
        dinv[n] = rsqrtf((float)v + 1.0f);
    }
    if (b == 0 && t == 0) rowptr[NNODES] = NEDGES;
    cur[t] = excl;
    __syncthreads();
    for (int i = t; i < S; i += 256) {
        unsigned pk = buck[s0 + i];
        int dl = (pk >> 16) & 255;
        int p = atomicAdd(&cur[dl], 1);
        ssrc[s0 + p] = (int)(pk & 0xFFFFu);
    }
}

// ------ gemm0: g16 = fp16((x @ W0) * dinv[row]) (R0, proven) -------------

__global__ __launch_bounds__(256) void k_gemm0(
    const float* __restrict__ x, const short* __restrict__ Bh,
    const short* __restrict__ Bl, const float* __restrict__ dinv,
    _Float16* __restrict__ g16) {
    __shared__ __align__(16) short sAh[64 * 64], sAl[64 * 64];
    __shared__ __align__(16) short sBh[128 * 64], sBl[128 * 64];
    const int t = threadIdx.x, lane = t & 63, w = t >> 6;
    const int row0 = blockIdx.x * 64;
    const int lr = lane >> 3, lz = lane & 7;
    const int swz = (lz ^ lr) * 8;
    const int fr = lane & 15, fq = lane >> 4;
    floatx4 acc[8] = {};
    const int ar = t >> 2, ac = t & 3;
    int garow = row0 + ar;
    if (garow >= NNODES) garow = NNODES - 1;
    const float* xrow = x + (size_t)garow * 256 + ac * 16;

    for (int k0 = 0; k0 < 256; k0 += 64) {
        const float4* xp = (const float4*)(xrow + k0);
        float4 f0 = xp[0], f1 = xp[1], f2 = xp[2], f3 = xp[3];
        float va[16] = {f0.x, f0.y, f0.z, f0.w, f1.x, f1.y, f1.z, f1.w,
                        f2.x, f2.y, f2.z, f2.w, f3.x, f3.y, f3.z, f3.w};
        short8 h0, h1, l0, l1;
#pragma unroll
        for (int j = 0; j < 8; j++) {
            short h, l;
            split_bf16(va[j], h, l);     h0[j] = h; l0[j] = l;
            split_bf16(va[8 + j], h, l); h1[j] = h; l1[j] = l;
        }
        int c0 = ac * 2;
        *(short8*)&sAh[ar * 64 + ((c0 ^ (ar & 7)) * 8)] = h0;
        *(short8*)&sAh[ar * 64 + (((c0 + 1) ^ (ar & 7)) * 8)] = h1;
        *(short8*)&sAl[ar * 64 + ((c0 ^ (ar & 7)) * 8)] = l0;
        *(short8*)&sAl[ar * 64 + (((c0 + 1) ^ (ar & 7)) * 8)] = l1;
#pragma unroll
        for (int jj = 0; jj < 4; jj++) {
            int j = w * 4 + jj;
            size_t go = (size_t)(j * 8 + lr) * 256 + k0 + swz;
            async16(&Bh[go], &sBh[j * 512 + lane * 8]);
            async16(&Bl[go], &sBl[j * 512 + lane * 8]);
        }
        __syncthreads();
#pragma unroll
        for (int ks = 0; ks < 2; ks++) {
            int R = w * 16 + fr;
            int ca = ((ks * 4 + fq) ^ (R & 7)) * 8;
            short8 ah = *(const short8*)&sAh[R * 64 + ca];
            short8 al = *(const short8*)&sAl[R * 64 + ca];
#pragma unroll
            for (int nt = 0; nt < 8; nt++) {
                int n = nt * 16 + fr;
                int cb = ((ks * 4 + fq) ^ (n & 7)) * 8;
                short8 bh = *(const short8*)&sBh[n * 64 + cb];
                short8 bl = *(const short8*)&sBl[n * 64 + cb];
                acc[nt] = __builtin_amdgcn_mfma_f32_16x16x32_bf16(ah, bh, acc[nt], 0, 0, 0);
                acc[nt] = __builtin_amdgcn_mfma_f32_16x16x32_bf16(ah, bl, acc[nt], 0, 0, 0);
                acc[nt] = __builtin_amdgcn_mfma_f32_16x16x32_bf16(al, bh, acc[nt], 0, 0, 0);
            }
        }
        __syncthreads();
    }
#pragma unroll
    for (int rr = 0; rr < 4; rr++) {
        int gw = row0 + w * 16 + fq * 4 + rr;
        if (gw < NNODES) {
            float dv = dinv[gw];
#pragma unroll
            for (int nt = 0; nt < 8; nt++)
                g16[(size_t)gw * 128 + nt * 16 + fr] =
                    (_Float16)(acc[nt][rr] * dv);
        }
    }
}

// ------ FUSED agg(layer L) + gemm(layer L+1) -----------------------------
// R5: gather concurrency doubled. Phase A is a single pass with 8
// threads/row x 32 rows; each thread owns TWO 16B chunks (c8, c8+8) ->
// 8 gather loads in flight per thread with the 4-edge unroll (R4 analysis:
// latency x concurrency bound, ~60 loads/SIMD needed, had ~25).
// LDS unchanged at 32KB (sED 8KB aliased into the 16KB B-union).

template <int BN>
__global__ __launch_bounds__(256) void k_fagg(
    const _Float16* __restrict__ gin,
    const int* __restrict__ ssrc,
    const int* __restrict__ rowptr,
    const float* __restrict__ dinv,
    const float* __restrict__ bias,
    const short* __restrict__ Bh, const short* __restrict__ Bl,
    _Float16* __restrict__ gout) {
    constexpr int BM = 32;
    constexpr int NT = BN / 32;          // col tiles per wave (4 or 2)
    __shared__ __align__(16) short sAh[2 * BM * 64], sAl[2 * BM * 64]; // 8+8 KB
    __shared__ __align__(16) char uB[16384];                          // 16 KB union

    const int t = threadIdx.x, lane = t & 63, w = t >> 6;
    const int row0 = blockIdx.x * BM;

    // ---- phase A: aggregate (single pass; sED aliases uB) ----
    int (*sED)[64] = (int(*)[64])uB;    // 32 x 64 ints = 8KB
    const int ln = t >> 3;      // row (0..31)
    const int c8 = t & 7;       // chunk pair: handles c8 and c8+8
    const f16x8* gp = (const f16x8*)gin;

    int gr = row0 + ln;
    if (gr >= NNODES) gr = NNODES - 1;
    int e0 = rowptr[gr], e1 = rowptr[gr + 1];
    int deg = e1 - e0;
    int cnt = deg < 64 ? deg : 64;
    for (int i = c8; i < cnt; i += 8) sED[ln][i] = ssrc[e0 + i];
    __syncthreads();

    f16x8 svA = gp[(size_t)gr * 16 + c8];          // self term
    f16x8 svB = gp[(size_t)gr * 16 + c8 + 8];
    float aA0[8], aA1[8], aB0[8], aB1[8];
#pragma unroll
    for (int j = 0; j < 8; j++) {
        aA0[j] = (float)svA[j]; aA1[j] = 0.f;
        aB0[j] = (float)svB[j]; aB1[j] = 0.f;
    }
    int i = 0;
    for (; i + 4 <= cnt; i += 4) {                 // 8 x 16B loads in flight
        int s0 = sED[ln][i],     s1 = sED[ln][i + 1];
        int s2 = sED[ln][i + 2], s3 = sED[ln][i + 3];
        f16x8 vA0 = gp[(size_t)s0 * 16 + c8];
        f16x8 vB0 = gp[(size_t)s0 * 16 + c8 + 8];
        f16x8 vA1 = gp[(size_t)s1 * 16 + c8];
        f16x8 vB1 = gp[(size_t)s1 * 16 + c8 + 8];
        f16x8 vA2 = gp[(size_t)s2 * 16 + c8];
        f16x8 vB2 = gp[(size_t)s2 * 16 + c8 + 8];
        f16x8 vA3 = gp[(size_t)s3 * 16 + c8];
        f16x8 vB3 = gp[(size_t)s3 * 16 + c8 + 8];
#pragma unroll
        for (int j = 0; j < 8; j++) {
            aA0[j] += (float)vA0[j] + (float)vA2[j];
            aA1[j] += (float)vA1[j] + (float)vA3[j];
            aB0[j] += (float)vB0[j] + (float)vB2[j];
            aB1[j] += (float)vB1[j] + (float)vB3[j];
        }
    }
    for (; i < cnt; i++) {
        int s = sED[ln][i];
        f16x8 vA = gp[(size_t)s * 16 + c8];
        f16x8 vB = gp[(size_t)s * 16 + c8 + 8];
#pragma unroll
        for (int j = 0; j < 8; j++) {
            aA0[j] += (float)vA[j];
            aB0[j] += (float)vB[j];
        }
    }
    for (int e = e0 + 64; e < e1; e++) {           // rare deg>64 overflow
        int s = ssrc[e];
        f16x8 vA = gp[(size_t)s * 16 + c8];
        f16x8 vB = gp[(size_t)s * 16 + c8 + 8];
#pragma unroll
        for (int j = 0; j < 8; j++) {
            aA0[j] += (float)vA[j];
            aB0[j] += (float)vB[j];
        }
    }

    {
        float dv = dinv[gr];
        short8 h8, l8;
#pragma unroll
        for (int j = 0; j < 8; j++) {
            float o = (aA0[j] + aA1[j]) * dv + bias[c8 * 8 + j];
            o = fmaxf(o, 0.f);                     // relu (both fused layers)
            short h, l;
            split_bf16(o, h, l);
            h8[j] = h; l8[j] = l;
        }
        int ao0 = ln * 64 + ((c8 ^ (ln & 7)) * 8); // K-tile 0, row ln, group c8
        *(short8*)&sAh[ao0] = h8;
        *(short8*)&sAl[ao0] = l8;
#pragma unroll
        for (int j = 0; j < 8; j++) {
            float o = (aB0[j] + aB1[j]) * dv + bias[(c8 + 8) * 8 + j];
            o = fmaxf(o, 0.f);
            short h, l;
            split_bf16(o, h, l);
            h8[j] = h; l8[j] = l;
        }
        int ao1 = BM * 64 + ao0;                   // K-tile 1
        *(short8*)&sAh[ao1] = h8;
        *(short8*)&sAl[ao1] = l8;
    }
    __syncthreads();                               // A ready; uB free for B

    // ---- phase B: gemm ----
    const int fr = lane & 15, fq = lane >> 4;
    const int lr = lane >> 3, lz = lane & 7;
    const int swz = (lz ^ lr) * 8;
    const int wr = w >> 1, wc = w & 1;
    floatx4 acc[NT] = {};

    if constexpr (BN == 128) {
        short* sB = (short*)uB;                    // one half: 128*64*2B = 16KB
#pragma unroll
        for (int kt = 0; kt < 2; kt++) {
            // stage H half
#pragma unroll
            for (int jj = 0; jj < 4; jj++) {
                int j = w * 4 + jj;
                size_t go = (size_t)(j * 8 + lr) * 128 + kt * 64 + swz;
                async16(&Bh[go], &sB[j * 512 + lane * 8]);
            }
            __syncthreads();
#pragma unroll
            for (int ks = 0; ks < 2; ks++) {
                int R = wr * 16 + fr;
                int ca = kt * (BM * 64) + R * 64 + (((ks * 4 + fq) ^ (R & 7)) * 8);
                short8 ah = *(const short8*)&sAh[ca];
                short8 al = *(const short8*)&sAl[ca];
#pragma unroll
                for (int nt = 0; nt < NT; nt++) {
                    int n = wc * (BN / 2) + nt * 16 + fr;
                    int cb = n * 64 + (((ks * 4 + fq) ^ (n & 7)) * 8);
                    short8 bh = *(const short8*)&sB[cb];
                    acc[nt] = __builtin_amdgcn_mfma_f32_16x16x32_bf16(ah, bh, acc[nt], 0, 0, 0);
                    acc[nt] = __builtin_amdgcn_mfma_f32_16x16x32_bf16(al, bh, acc[nt], 0, 0, 0);
                }
            }
            __syncthreads();
            // stage L half (same buffer)
#pragma unroll
            for (int jj = 0; jj < 4; jj++) {
                int j = w * 4 + jj;
                size_t go = (size_t)(j * 8 + lr) * 128 + kt * 64 + swz;
                async16(&Bl[go], &sB[j * 512 + lane * 8]);
            }
            __syncthreads();
#pragma unroll
            for (int ks = 0; ks < 2; ks++) {
                int R = wr * 16 + fr;
                int ca = kt * (BM * 64) + R * 64 + (((ks * 4 + fq) ^ (R & 7)) * 8);
                short8 ah = *(const short8*)&sAh[ca];
#pragma unroll
                for (int nt = 0; nt < NT; nt++) {
                    int n = wc * (BN / 2) + nt * 16 + fr;
                    int cb = n * 64 + (((ks * 4 + fq) ^ (n & 7)) * 8);
                    short8 bl = *(const short8*)&sB[cb];
                    acc[nt] = __builtin_amdgcn_mfma_f32_16x16x32_bf16(ah, bl, acc[nt], 0, 0, 0);
                }
            }
            __syncthreads();
        }
    } else {
        short* sBh_ = (short*)uB;                  // 64*64*2B = 8KB
        short* sBl_ = (short*)uB + 64 * 64;        // 8KB
#pragma unroll
        for (int kt = 0; kt < 2; kt++) {
#pragma unroll
            for (int jj = 0; jj < 2; jj++) {
                int j = w * 2 + jj;
                size_t go = (size_t)(j * 8 + lr) * 128 + kt * 64 + swz;
                async16(&Bh[go], &sBh_[j * 512 + lane * 8]);
                async16(&Bl[go], &sBl_[j * 512 + lane * 8]);
            }
            __syncthreads();
#pragma unroll
            for (int ks = 0; ks < 2; ks++) {
                int R = wr * 16 + fr;
                int ca = kt * (BM * 64) + R * 64 + (((ks * 4 + fq) ^ (R & 7)) * 8);
                short8 ah = *(const short8*)&sAh[ca];
                short8 al = *(const short8*)&sAl[ca];
#pragma unroll
                for (int nt = 0; nt < NT; nt++) {
                    int n = wc * (BN / 2) + nt * 16 + fr;
                    int cb = n * 64 + (((ks * 4 + fq) ^ (n & 7)) * 8);
                    short8 bh = *(const short8*)&sBh_[cb];
                    short8 bl = *(const short8*)&sBl_[cb];
                    acc[nt] = __builtin_amdgcn_mfma_f32_16x16x32_bf16(ah, bh, acc[nt], 0, 0, 0);
                    acc[nt] = __builtin_amdgcn_mfma_f32_16x16x32_bf16(ah, bl, acc[nt], 0, 0, 0);
                    acc[nt] = __builtin_amdgcn_mfma_f32_16x16x32_bf16(al, bh, acc[nt], 0, 0, 0);
                }
            }
            __syncthreads();
        }
    }

#pragma unroll
    for (int rr = 0; rr < 4; rr++) {
        int grow = row0 + wr * 16 + fq * 4 + rr;
        if (grow < NNODES) {
            float dv = dinv[grow];
#pragma unroll
            for (int nt = 0; nt < NT; nt++)
                gout[(size_t)grow * BN + wc * (BN / 2) + nt * 16 + fr] =
                    (_Float16)(acc[nt][rr] * dv);
        }
    }
}

// ------ Final aggregation (layer 2, F=64): dual-chunk gather, fp32 out ---
// R5: 4 threads/row x 64 nodes/block, 2 chunks/thread -> 8 loads in flight.

__global__ __launch_bounds__(256) void k_agg64(const _Float16* __restrict__ g,
                                               const int* __restrict__ ssrc,
                                               const int* __restrict__ rowptr,
                                               const float* __restrict__ dinv,
                                               const float* __restrict__ bias,
                                               float* __restrict__ outf) {
    constexpr int NPB = 64;
    __shared__ int sED[NPB][64];       // 16KB
    int t = threadIdx.x;
    int ln = t >> 2;                   // node (0..63)
    int c8 = t & 3;                    // chunk pair: c8 and c8+4 (of 8)
    int n = blockIdx.x * NPB + ln;
    bool valid = (n < NNODES);
    int nc = valid ? n : NNODES - 1;

    int e0 = rowptr[nc], e1 = rowptr[nc + 1];
    int deg = e1 - e0;
    int cnt = deg < 64 ? deg : 64;
    for (int i = c8; i < cnt; i += 4) sED[ln][i] = ssrc[e0 + i];
    __syncthreads();

    const f16x8* gp = (const f16x8*)g;
    f16x8 svA = gp[(size_t)nc * 8 + c8];          // self term
    f16x8 svB = gp[(size_t)nc * 8 + c8 + 4];
    float aA0[8], aA1[8], aB0[8], aB1[8];
#pragma unroll
    for (int j = 0; j < 8; j++) {
        aA0[j] = (float)svA[j]; aA1[j] = 0.f;
        aB0[j] = (float)svB[j]; aB1[j] = 0.f;
    }
    int i = 0;
    for (; i + 4 <= cnt; i += 4) {
        int s0 = sED[ln][i],     s1 = sED[ln][i + 1];
        int s2 = sED[ln][i + 2], s3 = sED[ln][i + 3];
        f16x8 vA0 = gp[(size_t)s0 * 8 + c8];
        f16x8 vB0 = gp[(size_t)s0 * 8 + c8 + 4];
        f16x8 vA1 = gp[(size_t)s1 * 8 + c8];
        f16x8 vB1 = gp[(size_t)s1 * 8 + c8 + 4];
        f16x8 vA2 = gp[(size_t)s2 * 8 + c8];
        f16x8 vB2 = gp[(size_t)s2 * 8 + c8 + 4];
        f16x8 vA3 = gp[(size_t)s3 * 8 + c8];
        f16x8 vB3 = gp[(size_t)s3 * 8 + c8 + 4];
#pragma unroll
        for (int j = 0; j < 8; j++) {
            aA0[j] += (float)vA0[j] + (float)vA2[j];
            aA1[j] += (float)vA1[j] + (float)vA3[j];
            aB0[j] += (float)vB0[j] + (float)vB2[j];
            aB1[j] += (float)vB1[j] + (float)vB3[j];
        }
    }
    for (; i < cnt; i++) {
        int s = sED[ln][i];
        f16x8 vA = gp[(size_t)s * 8 + c8];
        f16x8 vB = gp[(size_t)s * 8 + c8 + 4];
#pragma unroll
        for (int j = 0; j < 8; j++) {
            aA0[j] += (float)vA[j];
            aB0[j] += (float)vB[j];
        }
    }
    for (int e = e0 + 64; e < e1; e++) {
        int s = ssrc[e];
        f16x8 vA = gp[(size_t)s * 8 + c8];
        f16x8 vB = gp[(size_t)s * 8 + c8 + 4];
#pragma unroll
        for (int j = 0; j < 8; j++) {
            aA0[j] += (float)vA[j];
            aB0[j] += (float)vB[j];
        }
    }

    if (!valid) return;
    float dv = dinv[nc];
    float oA[8], oB[8];
#pragma unroll
    for (int j = 0; j < 8; j++) {
        oA[j] = (aA0[j] + aA1[j]) * dv + bias[c8 * 8 + j];
        oB[j] = (aB0[j] + aB1[j]) * dv + bias[(c8 + 4) * 8 + j];
    }
    *(float4*)&outf[(size_t)n * 64 + c8 * 8] =
        make_float4(oA[0], oA[1], oA[2], oA[3]);
    *(float4*)&outf[(size_t)n * 64 + c8 * 8 + 4] =
        make_float4(oA[4], oA[5], oA[6], oA[7]);
    *(float4*)&outf[(size_t)n * 64 + (c8 + 4) * 8] =
        make_float4(oB[0], oB[1], oB[2], oB[3]);
    *(float4*)&outf[(size_t)n * 64 + (c8 + 4) * 8 + 4] =
        make_float4(oB[4], oB[5], oB[6], oB[7]);
}

// ---------------- launch ----------------

static inline size_t align256(size_t x) { return (x + 255) & ~(size_t)255; }

extern "C" void kernel_launch(void* const* d_in, const int* in_sizes, int n_in,
                              void* d_out, int out_size, void* d_ws, size_t ws_size,
                              hipStream_t stream) {
    const float* x  = (const float*)d_in[0];
    const int*   ei = (const int*)d_in[1];
    const float* W0 = (const float*)d_in[2];
    const float* b0 = (const float*)d_in[3];
    const float* W1 = (const float*)d_in[4];
    const float* b1 = (const float*)d_in[5];
    const float* W2 = (const float*)d_in[6];
    const float* b2 = (const float*)d_in[7];
    float* out = (float*)d_out;

    const int* src = ei;
    const int* dst = ei + NEDGES;

    char* w = (char*)d_ws;
    size_t off = 0;
    float* dinv    = (float*)(w + off); off = align256(off + NNODES * 4);
    int* rowptr    = (int*)(w + off);   off = align256(off + (NNODES + 1) * 4);
    int* hist2d    = (int*)(w + off);   off = align256(off + 256 * 256 * 4);
    unsigned* buck = (unsigned*)(w + off); off = align256(off + (size_t)NEDGES * 4);
    int* ssrc      = (int*)(w + off);   off = align256(off + (size_t)NEDGES * 4);
    short* W0h     = (short*)(w + off); off = align256(off + 256 * 128 * 2);
    short* W0l     = (short*)(w + off); off = align256(off + 256 * 128 * 2);
    short* W1h     = (short*)(w + off); off = align256(off + 128 * 128 * 2);
    short* W1l     = (short*)(w + off); off = align256(off + 128 * 128 * 2);
    short* W2h     = (short*)(w + off); off = align256(off + 128 * 64 * 2);
    short* W2l     = (short*)(w + off); off = align256(off + 128 * 64 * 2);
    _Float16* g16a = (_Float16*)(w + off); off = align256(off + (size_t)NNODES * 128 * 2);
    _Float16* g16b = (_Float16*)(w + off); off = align256(off + (size_t)NNODES * 128 * 2);
    _Float16* g16c = (_Float16*)(w + off); off = align256(off + (size_t)NNODES * 64 * 2);

    const int MB = (NNODES + 63) / 64;            // 782
    const int FB = (NNODES + 31) / 32;            // 1563 (fused, 32 rows/block)
    const int AB = (NNODES + 63) / 64;            // 782 (final agg, 64 nodes/block)

    // 1) prep: weights + coarse histogram
    k_prep<<<PREP_TOT, 256, 0, stream>>>(W0, W0h, W0l, W1, W1h, W1l,
                                         W2, W2h, W2l, dst, hist2d);
    // 2) coarse scatter
    k_p2<<<256, 256, 0, stream>>>(src, dst, hist2d, buck);
    // 3) finalize: rowptr/dinv/ssrc
    k_p3<<<256, 256, 0, stream>>>(buck, hist2d, rowptr, dinv, ssrc);

    // layer 0 gemm (direct x)
    k_gemm0<<<MB, 256, 0, stream>>>(x, W0h, W0l, dinv, g16a);
    // fused: agg0 (+b0, relu) -> gemm1 -> g16b
    k_fagg<128><<<FB, 256, 0, stream>>>(g16a, ssrc, rowptr, dinv, b0,
                                        W1h, W1l, g16b);
    // fused: agg1 (+b1, relu) -> gemm2 -> g16c
    k_fagg<64><<<FB, 256, 0, stream>>>(g16b, ssrc, rowptr, dinv, b1,
                                       W2h, W2l, g16c);
    // final: agg2 (+b2, no relu) -> fp32 out
    k_agg64<<<AB, 256, 0, stream>>>(g16c, ssrc, rowptr, dinv, b2, out);
    (void)in_sizes; (void)n_in; (void)out_size; (void)ws_size;
}